// Round 4
// baseline (475.522 us; speedup 1.0000x reference)
//
#include <hip/hip_runtime.h>

// ---------------------------------------------------------------------------
// LinearAttention on MI355X (gfx950), round 4.
//  - fill writes moved to kernel EPILOGUES (no vmcnt-store drain in K-loops),
//    spread across proj/fm/kv_partial/context/output kernels
//  - XCD-bijective blockIdx swizzle on the two big GEMMs (T1)
//  - prep kernel fuses cvt3 + all weight transposes; denom folded into
//    kv_reduce. 7 launches total.
// ---------------------------------------------------------------------------

typedef __bf16 bf16_t;
typedef __bf16 bf16x8 __attribute__((ext_vector_type(8)));
typedef __bf16 bf16x4 __attribute__((ext_vector_type(4)));
typedef float  f32x4  __attribute__((ext_vector_type(4)));

#define FILLV (1.0f / 2048.0f)

// async global->LDS, 16B per lane. LDS dest must be linear: base + lane*16.
__device__ __forceinline__ void gload16(const void* g, void* l) {
  __builtin_amdgcn_global_load_lds(
      (__attribute__((address_space(1))) void*)(g),
      (__attribute__((address_space(3))) void*)(l), 16, 0, 0);
}

__device__ __forceinline__ void fill_epilogue(float* attn, long slotBase,
                                              int slots, int t) {
  const f32x4 fv = {FILLV, FILLV, FILLV, FILLV};
  f32x4* dst = (f32x4*)attn + slotBase + t;
  for (int i = 0; i < slots; i += 256)
    __builtin_nontemporal_store(fv, dst + i);
}

// ---------------------------------------------------------------------------
// m97-style bf16 GEMM, C[M,N] = A[M,K] @ Bt[N,K]^T (+bias).
// 128x128 tile, BK=64, 256 threads (4 waves 2x2), 4x4 16x16x32 frags/wave.
// FILL: writes fillPerBlock f32x4 slots of attn in the epilogue.
// XCDSWZ: bijective XCD swizzle of (by,bx); requires gridDim.z==1, nwg%8==0.
// ---------------------------------------------------------------------------
template<bool RELU, bool OUTF32, bool BIAS, bool FILL, bool XCDSWZ>
__global__ __launch_bounds__(256) void gemm_bt(
    const bf16_t* __restrict__ A, const bf16_t* __restrict__ Bt,
    const float* __restrict__ bias, void* __restrict__ C,
    int K, int lda, int ldb, int ldc,
    long aBatchB, long aBatchH, long bBatchB, long bBatchH,
    long cBatchB, long cBatchH, int HperB,
    float* __restrict__ attn, long fillBase, int fillPerBlock)
{
  __shared__ bf16_t As[128 * 64];
  __shared__ bf16_t Bs[128 * 64];

  const int t = threadIdx.x;
  const int lane = t & 63, w = t >> 6;
  const int wm = (w >> 1) * 64, wn = (w & 1) * 64;

  const int p = ((int)blockIdx.z * gridDim.y + blockIdx.y) * gridDim.x
                + blockIdx.x;
  int bx = blockIdx.x, by = blockIdx.y;
  if constexpr (XCDSWZ) {
    const int nwg = gridDim.x * gridDim.y;
    const int qq  = nwg >> 3;
    const int tl  = (p & 7) * qq + (p >> 3);
    by = tl / gridDim.x;
    bx = tl % gridDim.x;
  }

  const int z  = blockIdx.z;
  const int zb = z / HperB, zh = z % HperB;
  const bf16_t* Ab = A  + (long)zb * aBatchB + (long)zh * aBatchH
                        + (long)by * 128 * lda;
  const bf16_t* Bb = Bt + (long)zb * bBatchB + (long)zh * bBatchH
                        + (long)bx * 128 * ldb;

  f32x4 acc[4][4];
#pragma unroll
  for (int i = 0; i < 4; ++i)
#pragma unroll
    for (int j = 0; j < 4; ++j) acc[i][j] = (f32x4){0.f, 0.f, 0.f, 0.f};

  for (int k0 = 0; k0 < K; k0 += 64) {
#pragma unroll
    for (int i = 0; i < 4; ++i) {
      int c = i * 256 + t;
      int row = c >> 3, col = (c & 7) * 8;
      gload16(Ab + (long)row * lda + k0 + col, &As[c * 8]);
      gload16(Bb + (long)row * ldb + k0 + col, &Bs[c * 8]);
    }
    __syncthreads();
#pragma unroll
    for (int kk = 0; kk < 2; ++kk) {
      bf16x8 af[4], bfr[4];
#pragma unroll
      for (int mi = 0; mi < 4; ++mi)
        af[mi] = *(const bf16x8*)&As[(wm + mi * 16 + (lane & 15)) * 64
                                     + kk * 32 + (lane >> 4) * 8];
#pragma unroll
      for (int ni = 0; ni < 4; ++ni)
        bfr[ni] = *(const bf16x8*)&Bs[(wn + ni * 16 + (lane & 15)) * 64
                                      + kk * 32 + (lane >> 4) * 8];
#pragma unroll
      for (int mi = 0; mi < 4; ++mi)
#pragma unroll
        for (int ni = 0; ni < 4; ++ni)
          acc[mi][ni] = __builtin_amdgcn_mfma_f32_16x16x32_bf16(
              af[mi], bfr[ni], acc[mi][ni], 0, 0, 0);
    }
    __syncthreads();
  }

  if constexpr (FILL)
    fill_epilogue(attn, fillBase + (long)p * fillPerBlock, fillPerBlock, t);

  const long cb = (long)zb * cBatchB + (long)zh * cBatchH;
  const int row0 = by * 128 + wm;
  const int col0 = bx * 128 + wn;
#pragma unroll
  for (int mi = 0; mi < 4; ++mi) {
#pragma unroll
    for (int ni = 0; ni < 4; ++ni) {
      const int col = col0 + ni * 16 + (lane & 15);
      const float bv = BIAS ? bias[col] : 0.f;
#pragma unroll
      for (int j = 0; j < 4; ++j) {
        const int row = row0 + mi * 16 + (lane >> 4) * 4 + j;
        float v = acc[mi][ni][j] + bv;
        if (RELU) v = fmaxf(v, 0.f);
        if (OUTF32) ((float*)C)[cb + (long)row * ldc + col] = v;
        else        ((bf16_t*)C)[cb + (long)row * ldc + col] = (bf16_t)v;
      }
    }
  }
}

// ---------------------------------------------------------------------------
// Fused Q/K/V projection, grid (16, 96); XCD swizzle; epilogue fill.
// ---------------------------------------------------------------------------
__global__ __launch_bounds__(256) void proj_gemm(
    const bf16_t* __restrict__ A,    // [12288][2048] stacked q,k,v (bf16)
    const bf16_t* __restrict__ Wt,   // [3][2048][2048] Wq_t,Wk_t,Wv_t
    const float* __restrict__ bq, const float* __restrict__ bk,
    const float* __restrict__ bv,
    bf16_t* __restrict__ C,          // [12288][2048] stacked Qp,Kp,Vp
    float* __restrict__ attn)
{
  __shared__ bf16_t As[128 * 64];
  __shared__ bf16_t Bs[128 * 64];

  const int t = threadIdx.x;
  const int lane = t & 63, w = t >> 6;
  const int wm = (w >> 1) * 64, wn = (w & 1) * 64;

  const int p  = blockIdx.y * 16 + blockIdx.x;       // 0..1535 physical
  const int tl = (p & 7) * 192 + (p >> 3);           // bijective (1536=8*192)
  const int by = tl >> 4, bx = tl & 15;

  const int which = by >> 5;
  const bf16_t* Ab = A + (long)by * 128 * 2048;
  const bf16_t* Bb = Wt + (long)which * 4194304 + (long)bx * 128 * 2048;
  const float* bias = which == 0 ? bq : (which == 1 ? bk : bv);

  f32x4 acc[4][4];
#pragma unroll
  for (int i = 0; i < 4; ++i)
#pragma unroll
    for (int j = 0; j < 4; ++j) acc[i][j] = (f32x4){0.f, 0.f, 0.f, 0.f};

  for (int k0 = 0; k0 < 2048; k0 += 64) {
#pragma unroll
    for (int i = 0; i < 4; ++i) {
      int c = i * 256 + t;
      int row = c >> 3, col = (c & 7) * 8;
      gload16(Ab + (long)row * 2048 + k0 + col, &As[c * 8]);
      gload16(Bb + (long)row * 2048 + k0 + col, &Bs[c * 8]);
    }
    __syncthreads();
#pragma unroll
    for (int kk = 0; kk < 2; ++kk) {
      bf16x8 af[4], bfr[4];
#pragma unroll
      for (int mi = 0; mi < 4; ++mi)
        af[mi] = *(const bf16x8*)&As[(wm + mi * 16 + (lane & 15)) * 64
                                     + kk * 32 + (lane >> 4) * 8];
#pragma unroll
      for (int ni = 0; ni < 4; ++ni)
        bfr[ni] = *(const bf16x8*)&Bs[(wn + ni * 16 + (lane & 15)) * 64
                                      + kk * 32 + (lane >> 4) * 8];
#pragma unroll
      for (int mi = 0; mi < 4; ++mi)
#pragma unroll
        for (int ni = 0; ni < 4; ++ni)
          acc[mi][ni] = __builtin_amdgcn_mfma_f32_16x16x32_bf16(
              af[mi], bfr[ni], acc[mi][ni], 0, 0, 0);
    }
    __syncthreads();
  }

  // epilogue fill: slots [0, 12582912), 8192 per block (by physical id)
  fill_epilogue(attn, (long)p * 8192, 8192, t);

  const int row0 = by * 128 + wm;
  const int col0 = bx * 128 + wn;
#pragma unroll
  for (int mi = 0; mi < 4; ++mi) {
#pragma unroll
    for (int ni = 0; ni < 4; ++ni) {
      const int col = col0 + ni * 16 + (lane & 15);
      const float bvv = bias[col];
#pragma unroll
      for (int j = 0; j < 4; ++j) {
        const int row = row0 + mi * 16 + (lane >> 4) * 4 + j;
        C[(long)row * 2048 + col] = (bf16_t)(acc[mi][ni][j] + bvv);
      }
    }
  }
}

// ---------------------------------------------------------------------------
// Fused per-head feature map: Out = relu(A @ Wf1 + b1) @ Wf2 + b2.
// A/Out are [131072][128]; block = 64 rows; H [64][256] in swizzled LDS.
// Epilogue fill: slots [12582912, 20971520), 4096 per block.
// ---------------------------------------------------------------------------
__global__ __launch_bounds__(256) void fm_fused(
    const bf16_t* __restrict__ A, const bf16_t* __restrict__ W1t,
    const bf16_t* __restrict__ W2t, const float* __restrict__ b1,
    const float* __restrict__ b2, bf16_t* __restrict__ Out,
    float* __restrict__ attn)
{
  __shared__ char Hs[64 * 256 * 2];   // 32 KB
  const int t = threadIdx.x, lane = t & 63, w = t >> 6;
  const long r0 = (long)blockIdx.x * 64;
  const int lr = lane & 15, lk = lane >> 4;

  // phase A: H[64][256] = relu(A[64][128] @ W1t^T + b1)
  f32x4 acc[4][4];
#pragma unroll
  for (int i = 0; i < 4; ++i)
#pragma unroll
    for (int j = 0; j < 4; ++j) acc[i][j] = (f32x4){0.f, 0.f, 0.f, 0.f};
  const int wn = w * 64;
#pragma unroll
  for (int kk = 0; kk < 4; ++kk) {
    bf16x8 af[4], bfr[4];
#pragma unroll
    for (int mi = 0; mi < 4; ++mi)
      af[mi] = *(const bf16x8*)&A[(r0 + mi * 16 + lr) * 128 + kk * 32 + lk * 8];
#pragma unroll
    for (int ni = 0; ni < 4; ++ni)
      bfr[ni] = *(const bf16x8*)&W1t[(long)(wn + ni * 16 + lr) * 128
                                     + kk * 32 + lk * 8];
#pragma unroll
    for (int mi = 0; mi < 4; ++mi)
#pragma unroll
      for (int ni = 0; ni < 4; ++ni)
        acc[mi][ni] = __builtin_amdgcn_mfma_f32_16x16x32_bf16(
            af[mi], bfr[ni], acc[mi][ni], 0, 0, 0);
  }
#pragma unroll
  for (int ni = 0; ni < 4; ++ni) {
    const int col = wn + ni * 16 + lr;
    const float bvv = b1[col];
#pragma unroll
    for (int mi = 0; mi < 4; ++mi)
#pragma unroll
      for (int j = 0; j < 4; ++j) {
        const int row = mi * 16 + lk * 4 + j;
        float h = fmaxf(acc[mi][ni][j] + bvv, 0.f);
        int byte = (row << 9) + (col << 1);
        byte ^= (row & 7) << 4;                 // bank-conflict swizzle (G4)
        *(bf16_t*)(Hs + byte) = (bf16_t)h;
      }
  }
  __syncthreads();

  // phase B: C[64][128] = H @ W2t^T + b2
  f32x4 acc2[4][2];
#pragma unroll
  for (int i = 0; i < 4; ++i)
#pragma unroll
    for (int j = 0; j < 2; ++j) acc2[i][j] = (f32x4){0.f, 0.f, 0.f, 0.f};
  const int wn2 = w * 32;
#pragma unroll
  for (int kk = 0; kk < 8; ++kk) {
    bf16x8 af[4], bfr[2];
#pragma unroll
    for (int mi = 0; mi < 4; ++mi) {
      const int m = mi * 16 + lr;
      int byte = (m << 9) + kk * 64 + lk * 16;
      byte ^= (m & 7) << 4;
      af[mi] = *(const bf16x8*)(Hs + byte);
    }
#pragma unroll
    for (int ni = 0; ni < 2; ++ni)
      bfr[ni] = *(const bf16x8*)&W2t[(long)(wn2 + ni * 16 + lr) * 256
                                     + kk * 32 + lk * 8];
#pragma unroll
    for (int mi = 0; mi < 4; ++mi)
#pragma unroll
      for (int ni = 0; ni < 2; ++ni)
        acc2[mi][ni] = __builtin_amdgcn_mfma_f32_16x16x32_bf16(
            af[mi], bfr[ni], acc2[mi][ni], 0, 0, 0);
  }

  fill_epilogue(attn, 12582912L + (long)blockIdx.x * 4096, 4096, t);

#pragma unroll
  for (int ni = 0; ni < 2; ++ni) {
    const int col = wn2 + ni * 16 + lr;
    const float bvv = b2[col];
#pragma unroll
    for (int mi = 0; mi < 4; ++mi)
#pragma unroll
      for (int j = 0; j < 4; ++j) {
        const int row = mi * 16 + lk * 4 + j;
        Out[(r0 + row) * 128 + col] = (bf16_t)(acc2[mi][ni][j] + bvv);
      }
  }
}

// ---------------------------------------------------------------------------
// prep: fused fp32->bf16 cvt of q,k,v + all weight transpose-cvts.
// grid 41024 x 256 threads.
//  [0,24576)      cvt q,k,v (8192 blocks each)
//  [24576,40960)  transpose Wq,Wk,Wv,Wo (4096 blocks each, 64x64 tiles of 32)
//  [40960,40992)  transpose Wf1 (128x256)
//  [40992,41024)  transpose Wf2 (256x128)
// ---------------------------------------------------------------------------
__global__ __launch_bounds__(256) void prep(
    const float* __restrict__ q, const float* __restrict__ k,
    const float* __restrict__ v,
    const float* __restrict__ Wq, const float* __restrict__ Wk,
    const float* __restrict__ Wv, const float* __restrict__ Wo,
    const float* __restrict__ Wf1, const float* __restrict__ Wf2,
    bf16_t* __restrict__ qkv_bf, bf16_t* __restrict__ Wqkv_t,
    bf16_t* __restrict__ Wf1_t, bf16_t* __restrict__ Wf2_t)
{
  const int t = threadIdx.x;
  const int bid = blockIdx.x;
  __shared__ float tile[32][33];

  if (bid < 24576) {
    const float* in = bid < 8192 ? q : (bid < 16384 ? k : v);
    bf16_t* o = qkv_bf + (long)(bid >> 13) * 8388608L;
    long i = ((long)(bid & 8191) * 256 + t) * 4;
    float4 x = *(const float4*)&in[i];
    bf16x4 r = {(bf16_t)x.x, (bf16_t)x.y, (bf16_t)x.z, (bf16_t)x.w};
    *(bf16x4*)&o[i] = r;
    return;
  }

  const int x = t & 31, y = t >> 5;
  const float* W; bf16_t* out; int Kd, Nd, n0, k0;
  if (bid < 40960) {
    const int sub = bid - 24576;
    const int z = sub >> 12, r = sub & 4095;
    W = z == 0 ? Wq : z == 1 ? Wk : z == 2 ? Wv : Wo;
    out = Wqkv_t + (long)z * 4194304L;
    Kd = 2048; Nd = 2048;
    n0 = (r & 63) * 32; k0 = (r >> 6) * 32;
  } else if (bid < 40992) {
    const int sub = bid - 40960;
    W = Wf1; out = Wf1_t; Kd = 128; Nd = 256;
    n0 = (sub & 7) * 32; k0 = (sub >> 3) * 32;
  } else {
    const int sub = bid - 40992;
    W = Wf2; out = Wf2_t; Kd = 256; Nd = 128;
    n0 = (sub & 3) * 32; k0 = (sub >> 2) * 32;
  }
#pragma unroll
  for (int j = 0; j < 32; j += 8)
    tile[y + j][x] = W[(long)(k0 + y + j) * Nd + n0 + x];
  __syncthreads();
#pragma unroll
  for (int j = 0; j < 32; j += 8)
    out[(long)(n0 + y + j) * Kd + k0 + x] = (bf16_t)tile[x][y + j];
}

// ---------------------------------------------------------------------------
// Partial KV^T: part[sch][z][e][d] = sum_{s in chunk} V[s,e] * K[s,d].
// Epilogue fill: slots [29360128, 33554432), 8192 per block (512 blocks).
// ---------------------------------------------------------------------------
__global__ __launch_bounds__(256) void kv_partial(
    const bf16_t* __restrict__ Kf, const bf16_t* __restrict__ Vp,
    float* __restrict__ part, float* __restrict__ attn) {
  const int z = blockIdx.y, b = z >> 4, h = z & 15;
  const int s0 = blockIdx.x * 128;
  const int t = threadIdx.x;
  __shared__ bf16_t Ks[32 * 128];
  __shared__ bf16_t Vs[32 * 128];
  const bf16_t* Kb = Kf + (long)b * 4194304 + h * 128;
  const bf16_t* Vb = Vp + (long)b * 4194304 + h * 128;
  float acc[8][8];
#pragma unroll
  for (int i = 0; i < 8; ++i)
#pragma unroll
    for (int j = 0; j < 8; ++j) acc[i][j] = 0.f;
  const int d0 = (t & 15) * 8, e0 = (t >> 4) * 8;
  for (int sc = 0; sc < 128; sc += 32) {
#pragma unroll
    for (int i = 0; i < 2; ++i) {
      int idx = (i * 256 + t) * 8;
      int r = idx >> 7, c = idx & 127;
      long g = (long)(s0 + sc + r) * 2048 + c;
      *(bf16x8*)&Ks[r * 128 + c] = *(const bf16x8*)&Kb[g];
      *(bf16x8*)&Vs[r * 128 + c] = *(const bf16x8*)&Vb[g];
    }
    __syncthreads();
    for (int s = 0; s < 32; ++s) {
      bf16x8 kv = *(const bf16x8*)&Ks[s * 128 + d0];
      bf16x8 vv = *(const bf16x8*)&Vs[s * 128 + e0];
      float kf[8], vf[8];
#pragma unroll
      for (int i = 0; i < 8; ++i) { kf[i] = (float)kv[i]; vf[i] = (float)vv[i]; }
#pragma unroll
      for (int i = 0; i < 8; ++i)
#pragma unroll
        for (int j = 0; j < 8; ++j) acc[i][j] += vf[i] * kf[j];
    }
    __syncthreads();
  }

  fill_epilogue(attn,
      29360128L + (long)(blockIdx.y * 16 + blockIdx.x) * 8192, 8192, t);

  float* pb = part + ((long)blockIdx.x * 32 + z) * 16384;
#pragma unroll
  for (int i = 0; i < 8; ++i)
#pragma unroll
    for (int j = 0; j < 8; ++j)
      pb[(e0 + i) * 128 + (d0 + j)] = acc[i][j];
}

// ---------------------------------------------------------------------------
// kv_reduce (+ integrated denom): KVT[z][e][d] = (sum_sch part) / denom[z].
// ---------------------------------------------------------------------------
__global__ __launch_bounds__(256) void kv_reduce(
    const float* __restrict__ part, const bf16_t* __restrict__ Kf,
    bf16_t* __restrict__ KVT) {
  const int z = blockIdx.x, b = z >> 4, h = z & 15;
  const int t = threadIdx.x;

  // denom = sum over (s,d) of Kf[b,:,h,:] + 1e-8
  const bf16_t* base = Kf + (long)b * 4194304 + h * 128;
  float s = 0.f;
  for (int i = t; i < 2048 * 16; i += 256) {
    int r = i >> 4, seg = i & 15;
    bf16x8 vv = *(const bf16x8*)&base[(long)r * 2048 + seg * 8];
#pragma unroll
    for (int j = 0; j < 8; ++j) s += (float)vv[j];
  }
#pragma unroll
  for (int off = 32; off; off >>= 1) s += __shfl_down(s, off, 64);
  __shared__ float red[4];
  if ((t & 63) == 0) red[t >> 6] = s;
  __syncthreads();
  const float inv = 1.0f / (red[0] + red[1] + red[2] + red[3] + 1e-8f);

  for (int i = t; i < 16384; i += 256) {
    float acc = 0.f;
#pragma unroll
    for (int c = 0; c < 16; ++c) acc += part[((long)c * 32 + z) * 16384 + i];
    KVT[(long)z * 16384 + i] = (bf16_t)(acc * inv);
  }
}

// ---------------------------------------------------------------------------
extern "C" void kernel_launch(void* const* d_in, const int* in_sizes, int n_in,
                              void* d_out, int out_size, void* d_ws, size_t ws_size,
                              hipStream_t stream) {
  (void)in_sizes; (void)n_in; (void)out_size; (void)ws_size;
  const float* q   = (const float*)d_in[0];
  const float* k   = (const float*)d_in[1];
  const float* v   = (const float*)d_in[2];
  const float* Wq  = (const float*)d_in[3];
  const float* bq  = (const float*)d_in[4];
  const float* Wk  = (const float*)d_in[5];
  const float* bk  = (const float*)d_in[6];
  const float* Wv  = (const float*)d_in[7];
  const float* bv  = (const float*)d_in[8];
  const float* Wo  = (const float*)d_in[9];
  const float* bo  = (const float*)d_in[10];
  const float* Wf1 = (const float*)d_in[11];
  const float* bf1 = (const float*)d_in[12];
  const float* Wf2 = (const float*)d_in[13];
  const float* bf2 = (const float*)d_in[14];

  // ws layout (bf16 element offsets)
  bf16_t* P      = (bf16_t*)d_ws;
  bf16_t* qkv_bf = P;                  // [3][4096][2048] stacked q,k,v bf16
  bf16_t* Wqkv_t = P + 25165824L;      // [4][2048][2048] Wq_t,Wk_t,Wv_t,Wo_t
  bf16_t* Wo_t   = P + 37748736L;
  bf16_t* Wf1_t  = P + 41943040L;      // [256][128]
  bf16_t* Wf2_t  = P + 41975808L;      // [128][256]
  bf16_t* Qp     = P + 42008576L;      // [12288][2048] stacked Qp,Kp,Vp
  bf16_t* Vp     = P + 58785792L;      // later reused as context
  bf16_t* Qf     = P + 83951616L;      // [131072][128] stacked Qf,Kf
  bf16_t* Kf     = P + 92340224L;
  bf16_t* KVT    = P + 100728832L;     // [32][128][128]
  float*  part   = (float*)d_ws;       // [16][32][128][128] f32 over dead qkv_bf

  float* out0 = (float*)d_out;                 // [2,2048,2048]
  float* attn = (float*)d_out + 8388608L;      // [2,16,2048,2048]

  dim3 blk(256);

  // 1. prep: cvt q/k/v + all weight transposes
  prep<<<41024, blk, 0, stream>>>(q, k, v, Wq, Wk, Wv, Wo, Wf1, Wf2,
                                  qkv_bf, Wqkv_t, Wf1_t, Wf2_t);

  // 2. fused Q/K/V projection (+ fill slots [0, 12582912))
  proj_gemm<<<dim3(16, 96), blk, 0, stream>>>(
      qkv_bf, Wqkv_t, bq, bk, bv, Qp, attn);

  // 3. fused feature map over Qp||Kp -> Qf||Kf (+ fill [12582912, 20971520))
  fm_fused<<<2048, blk, 0, stream>>>(Qp, Wf1_t, Wf2_t, bf1, bf2, Qf, attn);

  // 4. KV^T partials (+ fill [29360128, 33554432))
  kv_partial<<<dim3(16, 32), blk, 0, stream>>>(Kf, Vp, part, attn);

  // 5. reduce + denom
  kv_reduce<<<32, blk, 0, stream>>>(part, Kf, KVT);

  // 6. context = Qf @ KVT^T batched (+ fill [20971520, 25165824))
  gemm_bt<false, false, false, true, false><<<dim3(1, 16, 32), blk, 0, stream>>>(
      Qf, KVT, nullptr, Vp, 128, 2048, 128, 2048,
      4194304L, 128L, 262144L, 16384L, 4194304L, 128L, 16,
      attn, 20971520L, 8192);

  // 7. output = context @ Wo + bo (+ fill [25165824, 29360128))
  gemm_bt<false, true, true, true, true><<<dim3(16, 32, 1), blk, 0, stream>>>(
      Vp, Wo_t, bo, out0, 2048, 2048, 2048, 2048, 0, 0, 0, 0, 0, 0, 1,
      attn, 25165824L, 8192);
}

// Round 5
// 363.845 us; speedup vs baseline: 1.3069x; 1.3069x over previous
//
#include <hip/hip_runtime.h>

// ---------------------------------------------------------------------------
// LinearAttention on MI355X (gfx950), round 5.
//  - fill back to R3's proven in-loop placement (merged vmcnt drain), proj +
//    output GEMMs only; no XCD swizzle (all panels L3-resident)
//  - prep kernel (fused cvt + transposes) kept from R4
//  - denom folded into kv_partial (K-tile already in LDS) -> part_denom
//  - kv_reduce now 512 blocks (full-GPU BW) with denom from part_denom
// ---------------------------------------------------------------------------

typedef __bf16 bf16_t;
typedef __bf16 bf16x8 __attribute__((ext_vector_type(8)));
typedef __bf16 bf16x4 __attribute__((ext_vector_type(4)));
typedef float  f32x4  __attribute__((ext_vector_type(4)));

#define FILLV (1.0f / 2048.0f)

// async global->LDS, 16B per lane. LDS dest must be linear: base + lane*16.
__device__ __forceinline__ void gload16(const void* g, void* l) {
  __builtin_amdgcn_global_load_lds(
      (__attribute__((address_space(1))) void*)(g),
      (__attribute__((address_space(3))) void*)(l), 16, 0, 0);
}

// ---------------------------------------------------------------------------
// m97-style bf16 GEMM, C[M,N] = A[M,K] @ Bt[N,K]^T (+bias).
// 128x128 tile, BK=64, 256 threads (4 waves 2x2), 4x4 16x16x32 frags/wave.
// FILL: 2 f32x4 attn-fill stores per thread per K-iter, issued in the load
// phase so the pre-barrier vmcnt(0) drain merges with the gload_lds drain.
// ---------------------------------------------------------------------------
template<bool RELU, bool OUTF32, bool BIAS, bool FILL>
__global__ __launch_bounds__(256) void gemm_bt(
    const bf16_t* __restrict__ A, const bf16_t* __restrict__ Bt,
    const float* __restrict__ bias, void* __restrict__ C,
    int K, int lda, int ldb, int ldc,
    long aBatchB, long aBatchH, long bBatchB, long bBatchH,
    long cBatchB, long cBatchH, int HperB,
    float* __restrict__ attn, long fillBase)
{
  __shared__ bf16_t As[128 * 64];
  __shared__ bf16_t Bs[128 * 64];

  const int z  = blockIdx.z;
  const int zb = z / HperB, zh = z % HperB;
  const bf16_t* Ab = A  + (long)zb * aBatchB + (long)zh * aBatchH
                        + (long)blockIdx.y * 128 * lda;
  const bf16_t* Bb = Bt + (long)zb * bBatchB + (long)zh * bBatchH
                        + (long)blockIdx.x * 128 * ldb;

  const int t = threadIdx.x;
  const int lane = t & 63, w = t >> 6;
  const int wm = (w >> 1) * 64, wn = (w & 1) * 64;

  f32x4 acc[4][4];
#pragma unroll
  for (int i = 0; i < 4; ++i)
#pragma unroll
    for (int j = 0; j < 4; ++j) acc[i][j] = (f32x4){0.f, 0.f, 0.f, 0.f};

  for (int k0 = 0; k0 < K; k0 += 64) {
#pragma unroll
    for (int i = 0; i < 4; ++i) {
      int c = i * 256 + t;
      int row = c >> 3, col = (c & 7) * 8;
      gload16(Ab + (long)row * lda + k0 + col, &As[c * 8]);
      gload16(Bb + (long)row * ldb + k0 + col, &Bs[c * 8]);
    }
    if constexpr (FILL) {
      const f32x4 fv = {FILLV, FILLV, FILLV, FILLV};
      const int wg = blockIdx.y * gridDim.x + blockIdx.x;
      const long nB = (long)gridDim.x * gridDim.y;
      long s0 = fillBase + (((long)(k0 >> 6) * nB + wg) * 2) * 256 + t;
      __builtin_nontemporal_store(fv, (f32x4*)attn + s0);
      __builtin_nontemporal_store(fv, (f32x4*)attn + s0 + 256);
    }
    __syncthreads();
#pragma unroll
    for (int kk = 0; kk < 2; ++kk) {
      bf16x8 af[4], bfr[4];
#pragma unroll
      for (int mi = 0; mi < 4; ++mi)
        af[mi] = *(const bf16x8*)&As[(wm + mi * 16 + (lane & 15)) * 64
                                     + kk * 32 + (lane >> 4) * 8];
#pragma unroll
      for (int ni = 0; ni < 4; ++ni)
        bfr[ni] = *(const bf16x8*)&Bs[(wn + ni * 16 + (lane & 15)) * 64
                                      + kk * 32 + (lane >> 4) * 8];
#pragma unroll
      for (int mi = 0; mi < 4; ++mi)
#pragma unroll
        for (int ni = 0; ni < 4; ++ni)
          acc[mi][ni] = __builtin_amdgcn_mfma_f32_16x16x32_bf16(
              af[mi], bfr[ni], acc[mi][ni], 0, 0, 0);
    }
    __syncthreads();
  }

  const long cb = (long)zb * cBatchB + (long)zh * cBatchH;
  const int row0 = blockIdx.y * 128 + wm;
  const int col0 = blockIdx.x * 128 + wn;
#pragma unroll
  for (int mi = 0; mi < 4; ++mi) {
#pragma unroll
    for (int ni = 0; ni < 4; ++ni) {
      const int col = col0 + ni * 16 + (lane & 15);
      const float bv = BIAS ? bias[col] : 0.f;
#pragma unroll
      for (int j = 0; j < 4; ++j) {
        const int row = row0 + mi * 16 + (lane >> 4) * 4 + j;
        float v = acc[mi][ni][j] + bv;
        if (RELU) v = fmaxf(v, 0.f);
        if (OUTF32) ((float*)C)[cb + (long)row * ldc + col] = v;
        else        ((bf16_t*)C)[cb + (long)row * ldc + col] = (bf16_t)v;
      }
    }
  }
}

// ---------------------------------------------------------------------------
// Fused Q/K/V projection, grid (16, 96); in-loop attn fill (slots
// [0, 25165824): 32 iters x 2 stores x 256 threads x 1536 blocks).
// ---------------------------------------------------------------------------
__global__ __launch_bounds__(256) void proj_gemm(
    const bf16_t* __restrict__ A,    // [12288][2048] stacked q,k,v (bf16)
    const bf16_t* __restrict__ Wt,   // [3][2048][2048] Wq_t,Wk_t,Wv_t
    const float* __restrict__ bq, const float* __restrict__ bk,
    const float* __restrict__ bv,
    bf16_t* __restrict__ C,          // [12288][2048] stacked Qp,Kp,Vp
    float* __restrict__ attn)
{
  __shared__ bf16_t As[128 * 64];
  __shared__ bf16_t Bs[128 * 64];

  const int t = threadIdx.x;
  const int lane = t & 63, w = t >> 6;
  const int wm = (w >> 1) * 64, wn = (w & 1) * 64;
  const int which = blockIdx.y >> 5;
  const bf16_t* Ab = A + (long)blockIdx.y * 128 * 2048;
  const bf16_t* Bb = Wt + (long)which * 4194304
                        + (long)blockIdx.x * 128 * 2048;
  const float* bias = which == 0 ? bq : (which == 1 ? bk : bv);
  const int wg = blockIdx.y * 16 + blockIdx.x;   // 0..1535
  const f32x4 fv = {FILLV, FILLV, FILLV, FILLV};

  f32x4 acc[4][4];
#pragma unroll
  for (int i = 0; i < 4; ++i)
#pragma unroll
    for (int j = 0; j < 4; ++j) acc[i][j] = (f32x4){0.f, 0.f, 0.f, 0.f};

  for (int k0 = 0; k0 < 2048; k0 += 64) {
#pragma unroll
    for (int i = 0; i < 4; ++i) {
      int c = i * 256 + t;
      int row = c >> 3, col = (c & 7) * 8;
      gload16(Ab + (long)row * 2048 + k0 + col, &As[c * 8]);
      gload16(Bb + (long)row * 2048 + k0 + col, &Bs[c * 8]);
    }
    {
      long s0 = (((long)(k0 >> 6) * 1536 + wg) * 2) * 256 + t;
      __builtin_nontemporal_store(fv, (f32x4*)attn + s0);
      __builtin_nontemporal_store(fv, (f32x4*)attn + s0 + 256);
    }
    __syncthreads();
#pragma unroll
    for (int kk = 0; kk < 2; ++kk) {
      bf16x8 af[4], bfr[4];
#pragma unroll
      for (int mi = 0; mi < 4; ++mi)
        af[mi] = *(const bf16x8*)&As[(wm + mi * 16 + (lane & 15)) * 64
                                     + kk * 32 + (lane >> 4) * 8];
#pragma unroll
      for (int ni = 0; ni < 4; ++ni)
        bfr[ni] = *(const bf16x8*)&Bs[(wn + ni * 16 + (lane & 15)) * 64
                                      + kk * 32 + (lane >> 4) * 8];
#pragma unroll
      for (int mi = 0; mi < 4; ++mi)
#pragma unroll
        for (int ni = 0; ni < 4; ++ni)
          acc[mi][ni] = __builtin_amdgcn_mfma_f32_16x16x32_bf16(
              af[mi], bfr[ni], acc[mi][ni], 0, 0, 0);
    }
    __syncthreads();
  }

  const int row0 = blockIdx.y * 128 + wm;
  const int col0 = blockIdx.x * 128 + wn;
#pragma unroll
  for (int mi = 0; mi < 4; ++mi) {
#pragma unroll
    for (int ni = 0; ni < 4; ++ni) {
      const int col = col0 + ni * 16 + (lane & 15);
      const float bvv = bias[col];
#pragma unroll
      for (int j = 0; j < 4; ++j) {
        const int row = row0 + mi * 16 + (lane >> 4) * 4 + j;
        C[(long)row * 2048 + col] = (bf16_t)(acc[mi][ni][j] + bvv);
      }
    }
  }
}

// ---------------------------------------------------------------------------
// Fused per-head feature map: Out = relu(A @ Wf1 + b1) @ Wf2 + b2.
// A/Out are [131072][128]; block = 64 rows; H [64][256] in swizzled LDS.
// ---------------------------------------------------------------------------
__global__ __launch_bounds__(256) void fm_fused(
    const bf16_t* __restrict__ A, const bf16_t* __restrict__ W1t,
    const bf16_t* __restrict__ W2t, const float* __restrict__ b1,
    const float* __restrict__ b2, bf16_t* __restrict__ Out)
{
  __shared__ char Hs[64 * 256 * 2];   // 32 KB
  const int t = threadIdx.x, lane = t & 63, w = t >> 6;
  const long r0 = (long)blockIdx.x * 64;
  const int lr = lane & 15, lk = lane >> 4;

  // phase A: H[64][256] = relu(A[64][128] @ W1t^T + b1)
  f32x4 acc[4][4];
#pragma unroll
  for (int i = 0; i < 4; ++i)
#pragma unroll
    for (int j = 0; j < 4; ++j) acc[i][j] = (f32x4){0.f, 0.f, 0.f, 0.f};
  const int wn = w * 64;
#pragma unroll
  for (int kk = 0; kk < 4; ++kk) {
    bf16x8 af[4], bfr[4];
#pragma unroll
    for (int mi = 0; mi < 4; ++mi)
      af[mi] = *(const bf16x8*)&A[(r0 + mi * 16 + lr) * 128 + kk * 32 + lk * 8];
#pragma unroll
    for (int ni = 0; ni < 4; ++ni)
      bfr[ni] = *(const bf16x8*)&W1t[(long)(wn + ni * 16 + lr) * 128
                                     + kk * 32 + lk * 8];
#pragma unroll
    for (int mi = 0; mi < 4; ++mi)
#pragma unroll
      for (int ni = 0; ni < 4; ++ni)
        acc[mi][ni] = __builtin_amdgcn_mfma_f32_16x16x32_bf16(
            af[mi], bfr[ni], acc[mi][ni], 0, 0, 0);
  }
#pragma unroll
  for (int ni = 0; ni < 4; ++ni) {
    const int col = wn + ni * 16 + lr;
    const float bvv = b1[col];
#pragma unroll
    for (int mi = 0; mi < 4; ++mi)
#pragma unroll
      for (int j = 0; j < 4; ++j) {
        const int row = mi * 16 + lk * 4 + j;
        float h = fmaxf(acc[mi][ni][j] + bvv, 0.f);
        int byte = (row << 9) + (col << 1);
        byte ^= (row & 7) << 4;                 // bank-conflict swizzle (G4)
        *(bf16_t*)(Hs + byte) = (bf16_t)h;
      }
  }
  __syncthreads();

  // phase B: C[64][128] = H @ W2t^T + b2
  f32x4 acc2[4][2];
#pragma unroll
  for (int i = 0; i < 4; ++i)
#pragma unroll
    for (int j = 0; j < 2; ++j) acc2[i][j] = (f32x4){0.f, 0.f, 0.f, 0.f};
  const int wn2 = w * 32;
#pragma unroll
  for (int kk = 0; kk < 8; ++kk) {
    bf16x8 af[4], bfr[2];
#pragma unroll
    for (int mi = 0; mi < 4; ++mi) {
      const int m = mi * 16 + lr;
      int byte = (m << 9) + kk * 64 + lk * 16;
      byte ^= (m & 7) << 4;
      af[mi] = *(const bf16x8*)(Hs + byte);
    }
#pragma unroll
    for (int ni = 0; ni < 2; ++ni)
      bfr[ni] = *(const bf16x8*)&W2t[(long)(wn2 + ni * 16 + lr) * 256
                                     + kk * 32 + lk * 8];
#pragma unroll
    for (int mi = 0; mi < 4; ++mi)
#pragma unroll
      for (int ni = 0; ni < 2; ++ni)
        acc2[mi][ni] = __builtin_amdgcn_mfma_f32_16x16x32_bf16(
            af[mi], bfr[ni], acc2[mi][ni], 0, 0, 0);
  }
#pragma unroll
  for (int ni = 0; ni < 2; ++ni) {
    const int col = wn2 + ni * 16 + lr;
    const float bvv = b2[col];
#pragma unroll
    for (int mi = 0; mi < 4; ++mi)
#pragma unroll
      for (int j = 0; j < 4; ++j) {
        const int row = mi * 16 + lk * 4 + j;
        Out[(r0 + row) * 128 + col] = (bf16_t)(acc2[mi][ni][j] + bvv);
      }
  }
}

// ---------------------------------------------------------------------------
// prep: fused fp32->bf16 cvt of q,k,v + all weight transpose-cvts.
// ---------------------------------------------------------------------------
__global__ __launch_bounds__(256) void prep(
    const float* __restrict__ q, const float* __restrict__ k,
    const float* __restrict__ v,
    const float* __restrict__ Wq, const float* __restrict__ Wk,
    const float* __restrict__ Wv, const float* __restrict__ Wo,
    const float* __restrict__ Wf1, const float* __restrict__ Wf2,
    bf16_t* __restrict__ qkv_bf, bf16_t* __restrict__ Wqkv_t,
    bf16_t* __restrict__ Wf1_t, bf16_t* __restrict__ Wf2_t)
{
  const int t = threadIdx.x;
  const int bid = blockIdx.x;
  __shared__ float tile[32][33];

  if (bid < 24576) {
    const float* in = bid < 8192 ? q : (bid < 16384 ? k : v);
    bf16_t* o = qkv_bf + (long)(bid >> 13) * 8388608L;
    long i = ((long)(bid & 8191) * 256 + t) * 4;
    float4 x = *(const float4*)&in[i];
    bf16x4 r = {(bf16_t)x.x, (bf16_t)x.y, (bf16_t)x.z, (bf16_t)x.w};
    *(bf16x4*)&o[i] = r;
    return;
  }

  const int x = t & 31, y = t >> 5;
  const float* W; bf16_t* out; int Kd, Nd, n0, k0;
  if (bid < 40960) {
    const int sub = bid - 24576;
    const int z = sub >> 12, r = sub & 4095;
    W = z == 0 ? Wq : z == 1 ? Wk : z == 2 ? Wv : Wo;
    out = Wqkv_t + (long)z * 4194304L;
    Kd = 2048; Nd = 2048;
    n0 = (r & 63) * 32; k0 = (r >> 6) * 32;
  } else if (bid < 40992) {
    const int sub = bid - 40960;
    W = Wf1; out = Wf1_t; Kd = 128; Nd = 256;
    n0 = (sub & 7) * 32; k0 = (sub >> 3) * 32;
  } else {
    const int sub = bid - 40992;
    W = Wf2; out = Wf2_t; Kd = 256; Nd = 128;
    n0 = (sub & 3) * 32; k0 = (sub >> 2) * 32;
  }
#pragma unroll
  for (int j = 0; j < 32; j += 8)
    tile[y + j][x] = W[(long)(k0 + y + j) * Nd + n0 + x];
  __syncthreads();
#pragma unroll
  for (int j = 0; j < 32; j += 8)
    out[(long)(n0 + y + j) * Kd + k0 + x] = (bf16_t)tile[x][y + j];
}

// ---------------------------------------------------------------------------
// Partial KV^T: part[sch][z][e][d] = sum_{s in chunk} V[s,e] * K[s,d].
// Also emits part_denom[sch][z] = sum over (s in chunk, d) of K (K-tile is
// already staged in LDS; 2 extra ds_read_b128 per thread per chunk).
// ---------------------------------------------------------------------------
__global__ __launch_bounds__(256) void kv_partial(
    const bf16_t* __restrict__ Kf, const bf16_t* __restrict__ Vp,
    float* __restrict__ part, float* __restrict__ part_denom) {
  const int z = blockIdx.y, b = z >> 4, h = z & 15;
  const int s0 = blockIdx.x * 128;
  const int t = threadIdx.x;
  __shared__ bf16_t Ks[32 * 128];
  __shared__ bf16_t Vs[32 * 128];
  __shared__ float red[4];
  const bf16_t* Kb = Kf + (long)b * 4194304 + h * 128;
  const bf16_t* Vb = Vp + (long)b * 4194304 + h * 128;
  float acc[8][8];
#pragma unroll
  for (int i = 0; i < 8; ++i)
#pragma unroll
    for (int j = 0; j < 8; ++j) acc[i][j] = 0.f;
  float ksum = 0.f;
  const int d0 = (t & 15) * 8, e0 = (t >> 4) * 8;
  for (int sc = 0; sc < 128; sc += 32) {
#pragma unroll
    for (int i = 0; i < 2; ++i) {
      int idx = (i * 256 + t) * 8;
      int r = idx >> 7, c = idx & 127;
      long g = (long)(s0 + sc + r) * 2048 + c;
      *(bf16x8*)&Ks[r * 128 + c] = *(const bf16x8*)&Kb[g];
      *(bf16x8*)&Vs[r * 128 + c] = *(const bf16x8*)&Vb[g];
    }
    __syncthreads();
    {
      // K-tile partial sum: thread t owns Ks[t*16 .. t*16+16)
      bf16x8 a0 = *(const bf16x8*)&Ks[t * 16];
      bf16x8 a1 = *(const bf16x8*)&Ks[t * 16 + 8];
#pragma unroll
      for (int j = 0; j < 8; ++j) ksum += (float)a0[j] + (float)a1[j];
    }
    for (int s = 0; s < 32; ++s) {
      bf16x8 kv = *(const bf16x8*)&Ks[s * 128 + d0];
      bf16x8 vv = *(const bf16x8*)&Vs[s * 128 + e0];
      float kf[8], vf[8];
#pragma unroll
      for (int i = 0; i < 8; ++i) { kf[i] = (float)kv[i]; vf[i] = (float)vv[i]; }
#pragma unroll
      for (int i = 0; i < 8; ++i)
#pragma unroll
        for (int j = 0; j < 8; ++j) acc[i][j] += vf[i] * kf[j];
    }
    __syncthreads();
  }

#pragma unroll
  for (int off = 32; off; off >>= 1) ksum += __shfl_down(ksum, off, 64);
  if ((t & 63) == 0) red[t >> 6] = ksum;
  __syncthreads();
  if (t == 0)
    part_denom[blockIdx.x * 32 + z] = red[0] + red[1] + red[2] + red[3];

  float* pb = part + ((long)blockIdx.x * 32 + z) * 16384;
#pragma unroll
  for (int i = 0; i < 8; ++i)
#pragma unroll
    for (int j = 0; j < 8; ++j)
      pb[(e0 + i) * 128 + (d0 + j)] = acc[i][j];
}

// ---------------------------------------------------------------------------
// kv_reduce: 512 blocks; z = bid>>4, slice = bid&15 (1024 elems each).
// KVT[z][e][d] = (sum_sch part) / (sum_sch part_denom + 1e-8).
// ---------------------------------------------------------------------------
__global__ __launch_bounds__(256) void kv_reduce(
    const float* __restrict__ part, const float* __restrict__ part_denom,
    bf16_t* __restrict__ KVT) {
  const int z = blockIdx.x >> 4, slice = blockIdx.x & 15;
  const int t = threadIdx.x;
  float dsum = 0.f;
#pragma unroll
  for (int c = 0; c < 16; ++c) dsum += part_denom[c * 32 + z];
  const float inv = 1.0f / (dsum + 1e-8f);
  const int base = slice * 1024;
  for (int i = base + t; i < base + 1024; i += 256) {
    float s = 0.f;
#pragma unroll
    for (int c = 0; c < 16; ++c) s += part[((long)c * 32 + z) * 16384 + i];
    KVT[(long)z * 16384 + i] = (bf16_t)(s * inv);
  }
}

// ---------------------------------------------------------------------------
extern "C" void kernel_launch(void* const* d_in, const int* in_sizes, int n_in,
                              void* d_out, int out_size, void* d_ws, size_t ws_size,
                              hipStream_t stream) {
  (void)in_sizes; (void)n_in; (void)out_size; (void)ws_size;
  const float* q   = (const float*)d_in[0];
  const float* k   = (const float*)d_in[1];
  const float* v   = (const float*)d_in[2];
  const float* Wq  = (const float*)d_in[3];
  const float* bq  = (const float*)d_in[4];
  const float* Wk  = (const float*)d_in[5];
  const float* bk  = (const float*)d_in[6];
  const float* Wv  = (const float*)d_in[7];
  const float* bv  = (const float*)d_in[8];
  const float* Wo  = (const float*)d_in[9];
  const float* bo  = (const float*)d_in[10];
  const float* Wf1 = (const float*)d_in[11];
  const float* bf1 = (const float*)d_in[12];
  const float* Wf2 = (const float*)d_in[13];
  const float* bf2 = (const float*)d_in[14];

  // ws layout (bf16 element offsets)
  bf16_t* P      = (bf16_t*)d_ws;
  bf16_t* qkv_bf = P;                  // [3][4096][2048] stacked q,k,v bf16
  bf16_t* Wqkv_t = P + 25165824L;      // [4][2048][2048] Wq_t,Wk_t,Wv_t,Wo_t
  bf16_t* Wo_t   = P + 37748736L;
  bf16_t* Wf1_t  = P + 41943040L;      // [256][128]
  bf16_t* Wf2_t  = P + 41975808L;      // [128][256]
  bf16_t* Qp     = P + 42008576L;      // [12288][2048] stacked Qp,Kp,Vp
  bf16_t* Vp     = P + 58785792L;      // later reused as context
  bf16_t* Qf     = P + 83951616L;      // [131072][128] stacked Qf,Kf
  bf16_t* Kf     = P + 92340224L;
  bf16_t* KVT    = P + 100728832L;     // [32][128][128]
  float*  part   = (float*)d_ws;       // [16][32][128][128] f32 over dead qkv_bf
  float*  part_denom = (float*)d_ws + 8388608L;   // [16][32] f32, after part

  float* out0 = (float*)d_out;                 // [2,2048,2048]
  float* attn = (float*)d_out + 8388608L;      // [2,16,2048,2048]

  dim3 blk(256);

  // 1. prep: cvt q/k/v + all weight transposes
  prep<<<41024, blk, 0, stream>>>(q, k, v, Wq, Wk, Wv, Wo, Wf1, Wf2,
                                  qkv_bf, Wqkv_t, Wf1_t, Wf2_t);

  // 2. fused Q/K/V projection (+ fill slots [0, 25165824))
  proj_gemm<<<dim3(16, 96), blk, 0, stream>>>(
      qkv_bf, Wqkv_t, bq, bk, bv, Qp, attn);

  // 3. fused feature map over Qp||Kp -> Qf||Kf
  fm_fused<<<2048, blk, 0, stream>>>(Qp, Wf1_t, Wf2_t, bf1, bf2, Qf);

  // 4. KV^T partials + per-chunk K-sums
  kv_partial<<<dim3(16, 32), blk, 0, stream>>>(Kf, Vp, part, part_denom);

  // 5. reduce partials (+denom), 512 blocks
  kv_reduce<<<512, blk, 0, stream>>>(part, part_denom, KVT);

  // 6. context = Qf @ KVT^T batched over 32 (b,h)
  gemm_bt<false, false, false, false><<<dim3(1, 16, 32), blk, 0, stream>>>(
      Qf, KVT, nullptr, Vp, 128, 2048, 128, 2048,
      4194304L, 128L, 262144L, 16384L, 4194304L, 128L, 16,
      nullptr, 0);

  // 7. output = context @ Wo + bo (+ fill slots [25165824, 33554432))
  gemm_bt<false, true, true, true><<<dim3(16, 32, 1), blk, 0, stream>>>(
      Vp, Wo_t, bo, out0, 2048, 2048, 2048, 2048, 0, 0, 0, 0, 0, 0, 1,
      attn, 25165824L);
}

// Round 6
// 359.512 us; speedup vs baseline: 1.3227x; 1.0121x over previous
//
#include <hip/hip_runtime.h>

// ---------------------------------------------------------------------------
// LinearAttention on MI355X (gfx950), round 6.
//  - proj GEMM ported to the 256x256 8-phase counted-vmcnt template
//    (T2 LDS swizzle + T3/T4 phases + T5 setprio), 512 thr, 128 KiB LDS dbuf
//  - fill redistributed: output in-loop 3/iter + epilogues on fm/kvp/kvr/ctx
//    + proj epilogue (exact 33,554,432-slot partition)
//  - everything else identical to round 5
// ---------------------------------------------------------------------------

typedef __bf16 bf16_t;
typedef __bf16 bf16x8 __attribute__((ext_vector_type(8)));
typedef __bf16 bf16x4 __attribute__((ext_vector_type(4)));
typedef float  f32x4  __attribute__((ext_vector_type(4)));

#define FILLV (1.0f / 2048.0f)

#define VMCNT2() asm volatile("s_waitcnt vmcnt(2)" ::: "memory")
#define VMCNT0() asm volatile("s_waitcnt vmcnt(0)" ::: "memory")
#define LGKM0()  asm volatile("s_waitcnt lgkmcnt(0)" ::: "memory")
#define BAR()    __builtin_amdgcn_s_barrier()
#define SCHED0() __builtin_amdgcn_sched_barrier(0)

// async global->LDS, 16B per lane. LDS dest must be linear: base + lane*16.
__device__ __forceinline__ void gload16(const void* g, void* l) {
  __builtin_amdgcn_global_load_lds(
      (__attribute__((address_space(1))) void*)(g),
      (__attribute__((address_space(3))) void*)(l), 16, 0, 0);
}

__device__ __forceinline__ void fill_epilogue(float* attn, long slotBase,
                                              int slots, int t) {
  const f32x4 fv = {FILLV, FILLV, FILLV, FILLV};
  f32x4* dst = (f32x4*)attn + slotBase + t;
  for (int i = 0; i < slots; i += 256)
    __builtin_nontemporal_store(fv, dst + i);
}

// ---------------------------------------------------------------------------
// 8-phase 256x256 proj GEMM. A [12288][2048] bf16, Wt [3][2048][2048] bf16.
// Grid 384 (bx=N/256 fastest), 512 threads = 8 waves (2M x 4N).
// LDS: [buf][A 32K | B 32K] x2 = 128 KiB. T2 swizzle: byte ^= (row&7)<<4,
// realized as inverse-swizzled global source (linear gload_lds dest) +
// swizzled ds_read address (rule #21).
// ---------------------------------------------------------------------------
__device__ __forceinline__ void stage_half(const bf16_t* __restrict__ g,
                                           int h, unsigned char* ldsT, int t) {
  const bf16_t* gh = g + (long)h * 128 * 2048;
  unsigned char* lh = ldsT + h * 16384;
#pragma unroll
  for (int i = 0; i < 2; ++i) {
    const int c = t + i * 512;           // chunk 0..1023 (16B each)
    const int r = c >> 3;                // row in half 0..127
    const int cc = ((c & 7) ^ (r & 7)) * 8;   // inverse-swizzled col (elems)
    gload16(gh + (long)r * 2048 + cc, lh + c * 16);
  }
}

__device__ __forceinline__ bf16x8 lds_frag(const unsigned char* base,
                                           int row, int kelem) {
  int byte = row * 128 + kelem * 2;
  byte ^= (row & 7) << 4;
  return *(const bf16x8*)(base + byte);
}

__global__ __launch_bounds__(512, 2) void proj_gemm8(
    const bf16_t* __restrict__ A, const bf16_t* __restrict__ Wt,
    const float* __restrict__ bq, const float* __restrict__ bk,
    const float* __restrict__ bv, bf16_t* __restrict__ C,
    float* __restrict__ attn)
{
  __shared__ __align__(16) unsigned char smem[131072];
  const int t = threadIdx.x;
  const int lane = t & 63;
  const int wid = t >> 6;
  const int wr = wid >> 2, wc = wid & 3;          // 2M x 4N wave grid
  const int bid = blockIdx.x;
  const int bx = bid & 7, by = bid >> 3;          // N=8 tiles, M=48 tiles
  const int which = by >> 4;                      // 16 M-tiles per weight
  const bf16_t* Ab = A + (long)by * 256 * 2048;
  const bf16_t* Bb = Wt + (long)which * 4194304 + (long)bx * 256 * 2048;
  const float* bias = which == 0 ? bq : (which == 1 ? bk : bv);

  const int lr = lane & 15;
  const int l8 = (lane >> 4) * 8;

  f32x4 acc[8][4];
#pragma unroll
  for (int i = 0; i < 8; ++i)
#pragma unroll
    for (int j = 0; j < 4; ++j) acc[i][j] = (f32x4){0.f, 0.f, 0.f, 0.f};

  // prologue: stage tile 0 into buffer 0 (8 loads/thread)
  stage_half(Ab, 0, smem, t);
  stage_half(Ab, 1, smem, t);
  stage_half(Bb, 0, smem + 32768, t);
  stage_half(Bb, 1, smem + 32768, t);

  bf16x8 aF[4][2], bF[4][2];

  for (int kt = 0; kt < 32; ++kt) {
    const int cur = kt & 1;
    unsigned char* curA = smem + cur * 65536;
    unsigned char* curB = curA + 32768;
    unsigned char* nxtA = smem + (cur ^ 1) * 65536;
    unsigned char* nxtB = nxtA + 32768;
    const bool hn = kt < 31;
    const bf16_t* An = Ab + (kt + 1) * 64;
    const bf16_t* Bn = Bb + (kt + 1) * 64;
    const int arow = wr * 128 + lr;
    const int brow = wc * 64 + lr;

    // ---- phase 0: stage A-h0(next); counted vmcnt; barrier; read aLo+bLo
    if (hn) { stage_half(An, 0, nxtA, t); VMCNT2(); }
    else    { VMCNT0(); }
    BAR();
#pragma unroll
    for (int mi = 0; mi < 4; ++mi)
#pragma unroll
      for (int kk = 0; kk < 2; ++kk)
        aF[mi][kk] = lds_frag(curA, arow + mi * 16, kk * 32 + l8);
#pragma unroll
    for (int ni = 0; ni < 2; ++ni)
#pragma unroll
      for (int kk = 0; kk < 2; ++kk)
        bF[ni][kk] = lds_frag(curB, brow + ni * 16, kk * 32 + l8);
    LGKM0(); SCHED0();
    __builtin_amdgcn_s_setprio(1);
#pragma unroll
    for (int mi = 0; mi < 4; ++mi)
#pragma unroll
      for (int ni = 0; ni < 2; ++ni)
#pragma unroll
        for (int kk = 0; kk < 2; ++kk)
          acc[mi][ni] = __builtin_amdgcn_mfma_f32_16x16x32_bf16(
              aF[mi][kk], bF[ni][kk], acc[mi][ni], 0, 0, 0);
    __builtin_amdgcn_s_setprio(0);
    BAR();

    // ---- phase 1: stage A-h1(next); read bHi; mfma quadrant (miLo, niHi)
    if (hn) stage_half(An, 1, nxtA, t);
#pragma unroll
    for (int ni = 0; ni < 2; ++ni)
#pragma unroll
      for (int kk = 0; kk < 2; ++kk)
        bF[2 + ni][kk] = lds_frag(curB, brow + (2 + ni) * 16, kk * 32 + l8);
    BAR(); LGKM0(); SCHED0();
    __builtin_amdgcn_s_setprio(1);
#pragma unroll
    for (int mi = 0; mi < 4; ++mi)
#pragma unroll
      for (int ni = 0; ni < 2; ++ni)
#pragma unroll
        for (int kk = 0; kk < 2; ++kk)
          acc[mi][2 + ni] = __builtin_amdgcn_mfma_f32_16x16x32_bf16(
              aF[mi][kk], bF[2 + ni][kk], acc[mi][2 + ni], 0, 0, 0);
    __builtin_amdgcn_s_setprio(0);
    BAR();

    // ---- phase 2: stage B-h0(next); read aHi; mfma quadrant (miHi, niLo)
    if (hn) stage_half(Bn, 0, nxtB, t);
#pragma unroll
    for (int mi = 0; mi < 4; ++mi)
#pragma unroll
      for (int kk = 0; kk < 2; ++kk)
        aF[mi][kk] = lds_frag(curA, arow + 64 + mi * 16, kk * 32 + l8);
    BAR(); LGKM0(); SCHED0();
    __builtin_amdgcn_s_setprio(1);
#pragma unroll
    for (int mi = 0; mi < 4; ++mi)
#pragma unroll
      for (int ni = 0; ni < 2; ++ni)
#pragma unroll
        for (int kk = 0; kk < 2; ++kk)
          acc[4 + mi][ni] = __builtin_amdgcn_mfma_f32_16x16x32_bf16(
              aF[mi][kk], bF[ni][kk], acc[4 + mi][ni], 0, 0, 0);
    __builtin_amdgcn_s_setprio(0);
    BAR();

    // ---- phase 3: stage B-h1(next); mfma quadrant (miHi, niHi)
    if (hn) stage_half(Bn, 1, nxtB, t);
    BAR(); LGKM0(); SCHED0();
    __builtin_amdgcn_s_setprio(1);
#pragma unroll
    for (int mi = 0; mi < 4; ++mi)
#pragma unroll
      for (int ni = 0; ni < 2; ++ni)
#pragma unroll
        for (int kk = 0; kk < 2; ++kk)
          acc[4 + mi][2 + ni] = __builtin_amdgcn_mfma_f32_16x16x32_bf16(
              aF[mi][kk], bF[2 + ni][kk], acc[4 + mi][2 + ni], 0, 0, 0);
    __builtin_amdgcn_s_setprio(0);
    BAR();
  }

  // epilogue fill: slots [27262976, 33554432), 16384 per block
  {
    const f32x4 fv = {FILLV, FILLV, FILLV, FILLV};
    f32x4* dst = (f32x4*)attn + 27262976L + (long)bid * 16384 + t;
#pragma unroll
    for (int i = 0; i < 16384; i += 512)
      __builtin_nontemporal_store(fv, dst + i);
  }

  // C write (+bias). D map: col=lane&15, row=(lane>>4)*4+j.
  const int row0 = by * 256 + wr * 128;
  const int col0 = bx * 256 + wc * 64;
#pragma unroll
  for (int mi = 0; mi < 8; ++mi) {
#pragma unroll
    for (int ni = 0; ni < 4; ++ni) {
      const int col = col0 + ni * 16 + lr;
      const float bvv = bias[col];
#pragma unroll
      for (int j = 0; j < 4; ++j) {
        const int row = row0 + mi * 16 + (lane >> 4) * 4 + j;
        C[(long)row * 2048 + col] = (bf16_t)(acc[mi][ni][j] + bvv);
      }
    }
  }
}

// ---------------------------------------------------------------------------
// m97-style bf16 GEMM, C[M,N] = A[M,K] @ Bt[N,K]^T (+bias).
// FILLMODE: 0 none, 1 in-loop 3 stores/iter, 2 epilogue (fillSlots/block).
// ---------------------------------------------------------------------------
template<bool RELU, bool OUTF32, bool BIAS, int FILLMODE>
__global__ __launch_bounds__(256) void gemm_bt(
    const bf16_t* __restrict__ A, const bf16_t* __restrict__ Bt,
    const float* __restrict__ bias, void* __restrict__ C,
    int K, int lda, int ldb, int ldc,
    long aBatchB, long aBatchH, long bBatchB, long bBatchH,
    long cBatchB, long cBatchH, int HperB,
    float* __restrict__ attn, long fillBase, int fillSlots)
{
  __shared__ bf16_t As[128 * 64];
  __shared__ bf16_t Bs[128 * 64];

  const int z  = blockIdx.z;
  const int zb = z / HperB, zh = z % HperB;
  const bf16_t* Ab = A  + (long)zb * aBatchB + (long)zh * aBatchH
                        + (long)blockIdx.y * 128 * lda;
  const bf16_t* Bb = Bt + (long)zb * bBatchB + (long)zh * bBatchH
                        + (long)blockIdx.x * 128 * ldb;

  const int t = threadIdx.x;
  const int lane = t & 63, w = t >> 6;
  const int wm = (w >> 1) * 64, wn = (w & 1) * 64;
  const int p = ((int)blockIdx.z * gridDim.y + blockIdx.y) * gridDim.x
                + blockIdx.x;

  f32x4 acc[4][4];
#pragma unroll
  for (int i = 0; i < 4; ++i)
#pragma unroll
    for (int j = 0; j < 4; ++j) acc[i][j] = (f32x4){0.f, 0.f, 0.f, 0.f};

  for (int k0 = 0; k0 < K; k0 += 64) {
#pragma unroll
    for (int i = 0; i < 4; ++i) {
      int c = i * 256 + t;
      int row = c >> 3, col = (c & 7) * 8;
      gload16(Ab + (long)row * lda + k0 + col, &As[c * 8]);
      gload16(Bb + (long)row * ldb + k0 + col, &Bs[c * 8]);
    }
    if constexpr (FILLMODE == 1) {
      const f32x4 fv = {FILLV, FILLV, FILLV, FILLV};
      const long nB = (long)gridDim.x * gridDim.y * gridDim.z;
      long s0 = fillBase + (((long)(k0 >> 6) * nB + p) * 3) * 256 + t;
      __builtin_nontemporal_store(fv, (f32x4*)attn + s0);
      __builtin_nontemporal_store(fv, (f32x4*)attn + s0 + 256);
      __builtin_nontemporal_store(fv, (f32x4*)attn + s0 + 512);
    }
    __syncthreads();
#pragma unroll
    for (int kk = 0; kk < 2; ++kk) {
      bf16x8 af[4], bfr[4];
#pragma unroll
      for (int mi = 0; mi < 4; ++mi)
        af[mi] = *(const bf16x8*)&As[(wm + mi * 16 + (lane & 15)) * 64
                                     + kk * 32 + (lane >> 4) * 8];
#pragma unroll
      for (int ni = 0; ni < 4; ++ni)
        bfr[ni] = *(const bf16x8*)&Bs[(wn + ni * 16 + (lane & 15)) * 64
                                      + kk * 32 + (lane >> 4) * 8];
#pragma unroll
      for (int mi = 0; mi < 4; ++mi)
#pragma unroll
        for (int ni = 0; ni < 4; ++ni)
          acc[mi][ni] = __builtin_amdgcn_mfma_f32_16x16x32_bf16(
              af[mi], bfr[ni], acc[mi][ni], 0, 0, 0);
    }
    __syncthreads();
  }

  if constexpr (FILLMODE == 2)
    fill_epilogue(attn, fillBase + (long)p * fillSlots, fillSlots, t);

  const long cb = (long)zb * cBatchB + (long)zh * cBatchH;
  const int row0 = blockIdx.y * 128 + wm;
  const int col0 = blockIdx.x * 128 + wn;
#pragma unroll
  for (int mi = 0; mi < 4; ++mi) {
#pragma unroll
    for (int ni = 0; ni < 4; ++ni) {
      const int col = col0 + ni * 16 + (lane & 15);
      const float bv = BIAS ? bias[col] : 0.f;
#pragma unroll
      for (int j = 0; j < 4; ++j) {
        const int row = row0 + mi * 16 + (lane >> 4) * 4 + j;
        float v = acc[mi][ni][j] + bv;
        if (RELU) v = fmaxf(v, 0.f);
        if (OUTF32) ((float*)C)[cb + (long)row * ldc + col] = v;
        else        ((bf16_t*)C)[cb + (long)row * ldc + col] = (bf16_t)v;
      }
    }
  }
}

// ---------------------------------------------------------------------------
// Fused per-head feature map: Out = relu(A @ Wf1 + b1) @ Wf2 + b2.
// ---------------------------------------------------------------------------
__global__ __launch_bounds__(256) void fm_fused(
    const bf16_t* __restrict__ A, const bf16_t* __restrict__ W1t,
    const bf16_t* __restrict__ W2t, const float* __restrict__ b1,
    const float* __restrict__ b2, bf16_t* __restrict__ Out,
    float* __restrict__ attn)
{
  __shared__ char Hs[64 * 256 * 2];   // 32 KB
  const int t = threadIdx.x, lane = t & 63, w = t >> 6;
  const long r0 = (long)blockIdx.x * 64;
  const int lr = lane & 15, lk = lane >> 4;

  f32x4 acc[4][4];
#pragma unroll
  for (int i = 0; i < 4; ++i)
#pragma unroll
    for (int j = 0; j < 4; ++j) acc[i][j] = (f32x4){0.f, 0.f, 0.f, 0.f};
  const int wn = w * 64;
#pragma unroll
  for (int kk = 0; kk < 4; ++kk) {
    bf16x8 af[4], bfr[4];
#pragma unroll
    for (int mi = 0; mi < 4; ++mi)
      af[mi] = *(const bf16x8*)&A[(r0 + mi * 16 + lr) * 128 + kk * 32 + lk * 8];
#pragma unroll
    for (int ni = 0; ni < 4; ++ni)
      bfr[ni] = *(const bf16x8*)&W1t[(long)(wn + ni * 16 + lr) * 128
                                     + kk * 32 + lk * 8];
#pragma unroll
    for (int mi = 0; mi < 4; ++mi)
#pragma unroll
      for (int ni = 0; ni < 4; ++ni)
        acc[mi][ni] = __builtin_amdgcn_mfma_f32_16x16x32_bf16(
            af[mi], bfr[ni], acc[mi][ni], 0, 0, 0);
  }
#pragma unroll
  for (int ni = 0; ni < 4; ++ni) {
    const int col = wn + ni * 16 + lr;
    const float bvv = b1[col];
#pragma unroll
    for (int mi = 0; mi < 4; ++mi)
#pragma unroll
      for (int j = 0; j < 4; ++j) {
        const int row = mi * 16 + lk * 4 + j;
        float h = fmaxf(acc[mi][ni][j] + bvv, 0.f);
        int byte = (row << 9) + (col << 1);
        byte ^= (row & 7) << 4;
        *(bf16_t*)(Hs + byte) = (bf16_t)h;
      }
  }
  __syncthreads();

  f32x4 acc2[4][2];
#pragma unroll
  for (int i = 0; i < 4; ++i)
#pragma unroll
    for (int j = 0; j < 2; ++j) acc2[i][j] = (f32x4){0.f, 0.f, 0.f, 0.f};
  const int wn2 = w * 32;
#pragma unroll
  for (int kk = 0; kk < 8; ++kk) {
    bf16x8 af[4], bfr[2];
#pragma unroll
    for (int mi = 0; mi < 4; ++mi) {
      const int m = mi * 16 + lr;
      int byte = (m << 9) + kk * 64 + lk * 16;
      byte ^= (m & 7) << 4;
      af[mi] = *(const bf16x8*)(Hs + byte);
    }
#pragma unroll
    for (int ni = 0; ni < 2; ++ni)
      bfr[ni] = *(const bf16x8*)&W2t[(long)(wn2 + ni * 16 + lr) * 256
                                     + kk * 32 + lk * 8];
#pragma unroll
    for (int mi = 0; mi < 4; ++mi)
#pragma unroll
      for (int ni = 0; ni < 2; ++ni)
        acc2[mi][ni] = __builtin_amdgcn_mfma_f32_16x16x32_bf16(
            af[mi], bfr[ni], acc2[mi][ni], 0, 0, 0);
  }

  // fill slots [12582912, 16777216), 2048/block
  fill_epilogue(attn, 12582912L + (long)blockIdx.x * 2048, 2048, t);

#pragma unroll
  for (int ni = 0; ni < 2; ++ni) {
    const int col = wn2 + ni * 16 + lr;
    const float bvv = b2[col];
#pragma unroll
    for (int mi = 0; mi < 4; ++mi)
#pragma unroll
      for (int j = 0; j < 4; ++j) {
        const int row = mi * 16 + lk * 4 + j;
        Out[(r0 + row) * 128 + col] = (bf16_t)(acc2[mi][ni][j] + bvv);
      }
  }
}

// ---------------------------------------------------------------------------
// prep: fused fp32->bf16 cvt of q,k,v + all weight transpose-cvts.
// ---------------------------------------------------------------------------
__global__ __launch_bounds__(256) void prep(
    const float* __restrict__ q, const float* __restrict__ k,
    const float* __restrict__ v,
    const float* __restrict__ Wq, const float* __restrict__ Wk,
    const float* __restrict__ Wv, const float* __restrict__ Wo,
    const float* __restrict__ Wf1, const float* __restrict__ Wf2,
    bf16_t* __restrict__ qkv_bf, bf16_t* __restrict__ Wqkv_t,
    bf16_t* __restrict__ Wf1_t, bf16_t* __restrict__ Wf2_t)
{
  const int t = threadIdx.x;
  const int bid = blockIdx.x;
  __shared__ float tile[32][33];

  if (bid < 24576) {
    const float* in = bid < 8192 ? q : (bid < 16384 ? k : v);
    bf16_t* o = qkv_bf + (long)(bid >> 13) * 8388608L;
    long i = ((long)(bid & 8191) * 256 + t) * 4;
    float4 x = *(const float4*)&in[i];
    bf16x4 r = {(bf16_t)x.x, (bf16_t)x.y, (bf16_t)x.z, (bf16_t)x.w};
    *(bf16x4*)&o[i] = r;
    return;
  }

  const int x = t & 31, y = t >> 5;
  const float* W; bf16_t* out; int Kd, Nd, n0, k0;
  if (bid < 40960) {
    const int sub = bid - 24576;
    const int z = sub >> 12, r = sub & 4095;
    W = z == 0 ? Wq : z == 1 ? Wk : z == 2 ? Wv : Wo;
    out = Wqkv_t + (long)z * 4194304L;
    Kd = 2048; Nd = 2048;
    n0 = (r & 63) * 32; k0 = (r >> 6) * 32;
  } else if (bid < 40992) {
    const int sub = bid - 40960;
    W = Wf1; out = Wf1_t; Kd = 128; Nd = 256;
    n0 = (sub & 7) * 32; k0 = (sub >> 3) * 32;
  } else {
    const int sub = bid - 40992;
    W = Wf2; out = Wf2_t; Kd = 256; Nd = 128;
    n0 = (sub & 3) * 32; k0 = (sub >> 2) * 32;
  }
#pragma unroll
  for (int j = 0; j < 32; j += 8)
    tile[y + j][x] = W[(long)(k0 + y + j) * Nd + n0 + x];
  __syncthreads();
#pragma unroll
  for (int j = 0; j < 32; j += 8)
    out[(long)(n0 + y + j) * Kd + k0 + x] = (bf16_t)tile[x][y + j];
}

// ---------------------------------------------------------------------------
// Partial KV^T + per-chunk K-sums.
// ---------------------------------------------------------------------------
__global__ __launch_bounds__(256) void kv_partial(
    const bf16_t* __restrict__ Kf, const bf16_t* __restrict__ Vp,
    float* __restrict__ part, float* __restrict__ part_denom,
    float* __restrict__ attn) {
  const int z = blockIdx.y, b = z >> 4, h = z & 15;
  const int s0 = blockIdx.x * 128;
  const int t = threadIdx.x;
  __shared__ bf16_t Ks[32 * 128];
  __shared__ bf16_t Vs[32 * 128];
  __shared__ float red[4];
  const bf16_t* Kb = Kf + (long)b * 4194304 + h * 128;
  const bf16_t* Vb = Vp + (long)b * 4194304 + h * 128;
  float acc[8][8];
#pragma unroll
  for (int i = 0; i < 8; ++i)
#pragma unroll
    for (int j = 0; j < 8; ++j) acc[i][j] = 0.f;
  float ksum = 0.f;
  const int d0 = (t & 15) * 8, e0 = (t >> 4) * 8;
  for (int sc = 0; sc < 128; sc += 32) {
#pragma unroll
    for (int i = 0; i < 2; ++i) {
      int idx = (i * 256 + t) * 8;
      int r = idx >> 7, c = idx & 127;
      long g = (long)(s0 + sc + r) * 2048 + c;
      *(bf16x8*)&Ks[r * 128 + c] = *(const bf16x8*)&Kb[g];
      *(bf16x8*)&Vs[r * 128 + c] = *(const bf16x8*)&Vb[g];
    }
    __syncthreads();
    {
      bf16x8 a0 = *(const bf16x8*)&Ks[t * 16];
      bf16x8 a1 = *(const bf16x8*)&Ks[t * 16 + 8];
#pragma unroll
      for (int j = 0; j < 8; ++j) ksum += (float)a0[j] + (float)a1[j];
    }
    for (int s = 0; s < 32; ++s) {
      bf16x8 kv = *(const bf16x8*)&Ks[s * 128 + d0];
      bf16x8 vv = *(const bf16x8*)&Vs[s * 128 + e0];
      float kf[8], vf[8];
#pragma unroll
      for (int i = 0; i < 8; ++i) { kf[i] = (float)kv[i]; vf[i] = (float)vv[i]; }
#pragma unroll
      for (int i = 0; i < 8; ++i)
#pragma unroll
        for (int j = 0; j < 8; ++j) acc[i][j] += vf[i] * kf[j];
    }
    __syncthreads();
  }

#pragma unroll
  for (int off = 32; off; off >>= 1) ksum += __shfl_down(ksum, off, 64);
  if ((t & 63) == 0) red[t >> 6] = ksum;
  __syncthreads();
  if (t == 0)
    part_denom[blockIdx.x * 32 + z] = red[0] + red[1] + red[2] + red[3];

  // fill slots [16777216, 20971520), 8192/block
  fill_epilogue(attn,
      16777216L + (long)(blockIdx.y * 16 + blockIdx.x) * 8192, 8192, t);

  float* pb = part + ((long)blockIdx.x * 32 + z) * 16384;
#pragma unroll
  for (int i = 0; i < 8; ++i)
#pragma unroll
    for (int j = 0; j < 8; ++j)
      pb[(e0 + i) * 128 + (d0 + j)] = acc[i][j];
}

// ---------------------------------------------------------------------------
// kv_reduce: 512 blocks; z = bid>>4, slice = bid&15.
// ---------------------------------------------------------------------------
__global__ __launch_bounds__(256) void kv_reduce(
    const float* __restrict__ part, const float* __restrict__ part_denom,
    bf16_t* __restrict__ KVT, float* __restrict__ attn) {
  const int z = blockIdx.x >> 4, slice = blockIdx.x & 15;
  const int t = threadIdx.x;
  float dsum = 0.f;
#pragma unroll
  for (int c = 0; c < 16; ++c) dsum += part_denom[c * 32 + z];
  const float inv = 1.0f / (dsum + 1e-8f);
  const int base = slice * 1024;
  for (int i = base + t; i < base + 1024; i += 256) {
    float s = 0.f;
#pragma unroll
    for (int c = 0; c < 16; ++c) s += part[((long)c * 32 + z) * 16384 + i];
    KVT[(long)z * 16384 + i] = (bf16_t)(s * inv);
  }
  // fill slots [20971520, 23068672), 4096/block
  fill_epilogue(attn, 20971520L + (long)blockIdx.x * 4096, 4096, t);
}

// ---------------------------------------------------------------------------
extern "C" void kernel_launch(void* const* d_in, const int* in_sizes, int n_in,
                              void* d_out, int out_size, void* d_ws, size_t ws_size,
                              hipStream_t stream) {
  (void)in_sizes; (void)n_in; (void)out_size; (void)ws_size;
  const float* q   = (const float*)d_in[0];
  const float* k   = (const float*)d_in[1];
  const float* v   = (const float*)d_in[2];
  const float* Wq  = (const float*)d_in[3];
  const float* bq  = (const float*)d_in[4];
  const float* Wk  = (const float*)d_in[5];
  const float* bk  = (const float*)d_in[6];
  const float* Wv  = (const float*)d_in[7];
  const float* bv  = (const float*)d_in[8];
  const float* Wo  = (const float*)d_in[9];
  const float* bo  = (const float*)d_in[10];
  const float* Wf1 = (const float*)d_in[11];
  const float* bf1 = (const float*)d_in[12];
  const float* Wf2 = (const float*)d_in[13];
  const float* bf2 = (const float*)d_in[14];

  bf16_t* P      = (bf16_t*)d_ws;
  bf16_t* qkv_bf = P;                  // [3][4096][2048]
  bf16_t* Wqkv_t = P + 25165824L;      // [4][2048][2048]
  bf16_t* Wo_t   = P + 37748736L;
  bf16_t* Wf1_t  = P + 41943040L;      // [256][128]
  bf16_t* Wf2_t  = P + 41975808L;      // [128][256]
  bf16_t* Qp     = P + 42008576L;      // [12288][2048] stacked Qp,Kp,Vp
  bf16_t* Vp     = P + 58785792L;      // later reused as context
  bf16_t* Qf     = P + 83951616L;      // [131072][128] stacked Qf,Kf
  bf16_t* Kf     = P + 92340224L;
  bf16_t* KVT    = P + 100728832L;     // [32][128][128]
  float*  part   = (float*)d_ws;       // [16][32][128][128] f32
  float*  part_denom = (float*)d_ws + 8388608L;   // [16][32]

  float* out0 = (float*)d_out;                 // [2,2048,2048]
  float* attn = (float*)d_out + 8388608L;      // [2,16,2048,2048]

  dim3 blk(256);

  // 1. prep: cvt q/k/v + weight transposes
  prep<<<41024, blk, 0, stream>>>(q, k, v, Wq, Wk, Wv, Wo, Wf1, Wf2,
                                  qkv_bf, Wqkv_t, Wf1_t, Wf2_t);

  // 2. 8-phase fused Q/K/V projection (+ fill [27262976, 33554432))
  proj_gemm8<<<384, 512, 0, stream>>>(qkv_bf, Wqkv_t, bq, bk, bv, Qp, attn);

  // 3. fused feature map (+ fill [12582912, 16777216))
  fm_fused<<<2048, blk, 0, stream>>>(Qp, Wf1_t, Wf2_t, bf1, bf2, Qf, attn);

  // 4. KV^T partials + K-sums (+ fill [16777216, 20971520))
  kv_partial<<<dim3(16, 32), blk, 0, stream>>>(Kf, Vp, part, part_denom, attn);

  // 5. reduce partials (+denom) (+ fill [20971520, 23068672))
  kv_reduce<<<512, blk, 0, stream>>>(part, part_denom, KVT, attn);

  // 6. context = Qf @ KVT^T batched (+ fill [23068672, 27262976), epilogue)
  gemm_bt<false, false, false, 2><<<dim3(1, 16, 32), blk, 0, stream>>>(
      Qf, KVT, nullptr, Vp, 128, 2048, 128, 2048,
      4194304L, 128L, 262144L, 16384L, 4194304L, 128L, 16,
      attn, 23068672L, 8192);

  // 7. output = context @ Wo + bo (+ fill [0, 12582912), in-loop 3/iter)
  gemm_bt<false, true, true, 1><<<dim3(16, 32, 1), blk, 0, stream>>>(
      Vp, Wo_t, bo, out0, 2048, 2048, 2048, 2048, 0, 0, 0, 0, 0, 0, 1,
      attn, 0L, 0);
}

// Round 7
// 348.308 us; speedup vs baseline: 1.3652x; 1.0322x over previous
//
#include <hip/hip_runtime.h>

// ---------------------------------------------------------------------------
// LinearAttention on MI355X (gfx950), round 7.
//  - 8-phase 256x256 proj GEMM kept (T2 swizzle + counted vmcnt + setprio)
//  - fill ONLY in compute-bound GEMMs: proj in-loop (phases 1-3, 18.87M
//    slots) + output in-loop (3/iter, 12.58M) + output epilogue (2.10M)
//  - fm / kv_partial / kv_reduce / ctx back to R5 no-fill forms
// ---------------------------------------------------------------------------

typedef __bf16 bf16_t;
typedef __bf16 bf16x8 __attribute__((ext_vector_type(8)));
typedef __bf16 bf16x4 __attribute__((ext_vector_type(4)));
typedef float  f32x4  __attribute__((ext_vector_type(4)));

#define FILLV (1.0f / 2048.0f)

#define VMCNT2() asm volatile("s_waitcnt vmcnt(2)" ::: "memory")
#define VMCNT0() asm volatile("s_waitcnt vmcnt(0)" ::: "memory")
#define LGKM0()  asm volatile("s_waitcnt lgkmcnt(0)" ::: "memory")
#define BAR()    __builtin_amdgcn_s_barrier()
#define SCHED0() __builtin_amdgcn_sched_barrier(0)

// async global->LDS, 16B per lane. LDS dest must be linear: base + lane*16.
__device__ __forceinline__ void gload16(const void* g, void* l) {
  __builtin_amdgcn_global_load_lds(
      (__attribute__((address_space(1))) void*)(g),
      (__attribute__((address_space(3))) void*)(l), 16, 0, 0);
}

// ---------------------------------------------------------------------------
// 8-phase 256x256 proj GEMM. A [12288][2048] bf16, Wt [3][2048][2048] bf16.
// Grid 384, 512 threads = 8 waves (2M x 4N). LDS 128 KiB dbuf.
// T2 swizzle via inverse-swizzled global source + XOR'd ds_read (rule #21).
// Fill: 3 stores/thread/K-tile in phases 1-3, slots [0, 18874368).
// ---------------------------------------------------------------------------
__device__ __forceinline__ void stage_half(const bf16_t* __restrict__ g,
                                           int h, unsigned char* ldsT, int t) {
  const bf16_t* gh = g + (long)h * 128 * 2048;
  unsigned char* lh = ldsT + h * 16384;
#pragma unroll
  for (int i = 0; i < 2; ++i) {
    const int c = t + i * 512;           // chunk 0..1023 (16B each)
    const int r = c >> 3;                // row in half 0..127
    const int cc = ((c & 7) ^ (r & 7)) * 8;   // inverse-swizzled col (elems)
    gload16(gh + (long)r * 2048 + cc, lh + c * 16);
  }
}

__device__ __forceinline__ bf16x8 lds_frag(const unsigned char* base,
                                           int row, int kelem) {
  int byte = row * 128 + kelem * 2;
  byte ^= (row & 7) << 4;
  return *(const bf16x8*)(base + byte);
}

__global__ __launch_bounds__(512, 2) void proj_gemm8(
    const bf16_t* __restrict__ A, const bf16_t* __restrict__ Wt,
    const float* __restrict__ bq, const float* __restrict__ bk,
    const float* __restrict__ bv, bf16_t* __restrict__ C,
    float* __restrict__ attn)
{
  __shared__ __align__(16) unsigned char smem[131072];
  const int t = threadIdx.x;
  const int lane = t & 63;
  const int wid = t >> 6;
  const int wr = wid >> 2, wc = wid & 3;          // 2M x 4N wave grid
  const int bid = blockIdx.x;
  const int bx = bid & 7, by = bid >> 3;          // N=8 tiles, M=48 tiles
  const int which = by >> 4;                      // 16 M-tiles per weight
  const bf16_t* Ab = A + (long)by * 256 * 2048;
  const bf16_t* Bb = Wt + (long)which * 4194304 + (long)bx * 256 * 2048;
  const float* bias = which == 0 ? bq : (which == 1 ? bk : bv);

  const int lr = lane & 15;
  const int l8 = (lane >> 4) * 8;
  const f32x4 fv = {FILLV, FILLV, FILLV, FILLV};

  f32x4 acc[8][4];
#pragma unroll
  for (int i = 0; i < 8; ++i)
#pragma unroll
    for (int j = 0; j < 4; ++j) acc[i][j] = (f32x4){0.f, 0.f, 0.f, 0.f};

  // prologue: stage tile 0 into buffer 0 (8 loads/thread)
  stage_half(Ab, 0, smem, t);
  stage_half(Ab, 1, smem, t);
  stage_half(Bb, 0, smem + 32768, t);
  stage_half(Bb, 1, smem + 32768, t);

  bf16x8 aF[4][2], bF[4][2];

  for (int kt = 0; kt < 32; ++kt) {
    const int cur = kt & 1;
    unsigned char* curA = smem + cur * 65536;
    unsigned char* curB = curA + 32768;
    unsigned char* nxtA = smem + (cur ^ 1) * 65536;
    unsigned char* nxtB = nxtA + 32768;
    const bool hn = kt < 31;
    const bf16_t* An = Ab + (kt + 1) * 64;
    const bf16_t* Bn = Bb + (kt + 1) * 64;
    const int arow = wr * 128 + lr;
    const int brow = wc * 64 + lr;
    f32x4* fillp = (f32x4*)attn + ((long)kt * 384 + bid) * 3 * 512 + t;

    // ---- phase 0: stage A-h0(next); counted vmcnt; barrier; read aLo+bLo
    if (hn) { stage_half(An, 0, nxtA, t); VMCNT2(); }
    else    { VMCNT0(); }
    BAR();
#pragma unroll
    for (int mi = 0; mi < 4; ++mi)
#pragma unroll
      for (int kk = 0; kk < 2; ++kk)
        aF[mi][kk] = lds_frag(curA, arow + mi * 16, kk * 32 + l8);
#pragma unroll
    for (int ni = 0; ni < 2; ++ni)
#pragma unroll
      for (int kk = 0; kk < 2; ++kk)
        bF[ni][kk] = lds_frag(curB, brow + ni * 16, kk * 32 + l8);
    LGKM0(); SCHED0();
    __builtin_amdgcn_s_setprio(1);
#pragma unroll
    for (int mi = 0; mi < 4; ++mi)
#pragma unroll
      for (int ni = 0; ni < 2; ++ni)
#pragma unroll
        for (int kk = 0; kk < 2; ++kk)
          acc[mi][ni] = __builtin_amdgcn_mfma_f32_16x16x32_bf16(
              aF[mi][kk], bF[ni][kk], acc[mi][ni], 0, 0, 0);
    __builtin_amdgcn_s_setprio(0);
    BAR();

    // ---- phase 1: stage A-h1(next) + fill; read bHi; mfma (miLo, niHi)
    if (hn) stage_half(An, 1, nxtA, t);
    __builtin_nontemporal_store(fv, fillp);
#pragma unroll
    for (int ni = 0; ni < 2; ++ni)
#pragma unroll
      for (int kk = 0; kk < 2; ++kk)
        bF[2 + ni][kk] = lds_frag(curB, brow + (2 + ni) * 16, kk * 32 + l8);
    BAR(); LGKM0(); SCHED0();
    __builtin_amdgcn_s_setprio(1);
#pragma unroll
    for (int mi = 0; mi < 4; ++mi)
#pragma unroll
      for (int ni = 0; ni < 2; ++ni)
#pragma unroll
        for (int kk = 0; kk < 2; ++kk)
          acc[mi][2 + ni] = __builtin_amdgcn_mfma_f32_16x16x32_bf16(
              aF[mi][kk], bF[2 + ni][kk], acc[mi][2 + ni], 0, 0, 0);
    __builtin_amdgcn_s_setprio(0);
    BAR();

    // ---- phase 2: stage B-h0(next) + fill; read aHi; mfma (miHi, niLo)
    if (hn) stage_half(Bn, 0, nxtB, t);
    __builtin_nontemporal_store(fv, fillp + 512);
#pragma unroll
    for (int mi = 0; mi < 4; ++mi)
#pragma unroll
      for (int kk = 0; kk < 2; ++kk)
        aF[mi][kk] = lds_frag(curA, arow + 64 + mi * 16, kk * 32 + l8);
    BAR(); LGKM0(); SCHED0();
    __builtin_amdgcn_s_setprio(1);
#pragma unroll
    for (int mi = 0; mi < 4; ++mi)
#pragma unroll
      for (int ni = 0; ni < 2; ++ni)
#pragma unroll
        for (int kk = 0; kk < 2; ++kk)
          acc[4 + mi][ni] = __builtin_amdgcn_mfma_f32_16x16x32_bf16(
              aF[mi][kk], bF[ni][kk], acc[4 + mi][ni], 0, 0, 0);
    __builtin_amdgcn_s_setprio(0);
    BAR();

    // ---- phase 3: stage B-h1(next) + fill; mfma (miHi, niHi)
    if (hn) stage_half(Bn, 1, nxtB, t);
    __builtin_nontemporal_store(fv, fillp + 1024);
    BAR(); LGKM0(); SCHED0();
    __builtin_amdgcn_s_setprio(1);
#pragma unroll
    for (int mi = 0; mi < 4; ++mi)
#pragma unroll
      for (int ni = 0; ni < 2; ++ni)
#pragma unroll
        for (int kk = 0; kk < 2; ++kk)
          acc[4 + mi][2 + ni] = __builtin_amdgcn_mfma_f32_16x16x32_bf16(
              aF[mi][kk], bF[2 + ni][kk], acc[4 + mi][2 + ni], 0, 0, 0);
    __builtin_amdgcn_s_setprio(0);
    BAR();
  }

  // C write (+bias). D map: col=lane&15, row=(lane>>4)*4+j.
  const int row0 = by * 256 + wr * 128;
  const int col0 = bx * 256 + wc * 64;
#pragma unroll
  for (int mi = 0; mi < 8; ++mi) {
#pragma unroll
    for (int ni = 0; ni < 4; ++ni) {
      const int col = col0 + ni * 16 + lr;
      const float bvv = bias[col];
#pragma unroll
      for (int j = 0; j < 4; ++j) {
        const int row = row0 + mi * 16 + (lane >> 4) * 4 + j;
        C[(long)row * 2048 + col] = (bf16_t)(acc[mi][ni][j] + bvv);
      }
    }
  }
}

// ---------------------------------------------------------------------------
// m97-style bf16 GEMM, C[M,N] = A[M,K] @ Bt[N,K]^T (+bias).
// FILLMODE: 0 none, 3 in-loop 3/iter + epilogue (fillSlots at fillBase2).
// ---------------------------------------------------------------------------
template<bool RELU, bool OUTF32, bool BIAS, int FILLMODE>
__global__ __launch_bounds__(256) void gemm_bt(
    const bf16_t* __restrict__ A, const bf16_t* __restrict__ Bt,
    const float* __restrict__ bias, void* __restrict__ C,
    int K, int lda, int ldb, int ldc,
    long aBatchB, long aBatchH, long bBatchB, long bBatchH,
    long cBatchB, long cBatchH, int HperB,
    float* __restrict__ attn, long fillBase, long fillBase2, int fillSlots)
{
  __shared__ bf16_t As[128 * 64];
  __shared__ bf16_t Bs[128 * 64];

  const int z  = blockIdx.z;
  const int zb = z / HperB, zh = z % HperB;
  const bf16_t* Ab = A  + (long)zb * aBatchB + (long)zh * aBatchH
                        + (long)blockIdx.y * 128 * lda;
  const bf16_t* Bb = Bt + (long)zb * bBatchB + (long)zh * bBatchH
                        + (long)blockIdx.x * 128 * ldb;

  const int t = threadIdx.x;
  const int lane = t & 63, w = t >> 6;
  const int wm = (w >> 1) * 64, wn = (w & 1) * 64;
  const int p = ((int)blockIdx.z * gridDim.y + blockIdx.y) * gridDim.x
                + blockIdx.x;

  f32x4 acc[4][4];
#pragma unroll
  for (int i = 0; i < 4; ++i)
#pragma unroll
    for (int j = 0; j < 4; ++j) acc[i][j] = (f32x4){0.f, 0.f, 0.f, 0.f};

  for (int k0 = 0; k0 < K; k0 += 64) {
#pragma unroll
    for (int i = 0; i < 4; ++i) {
      int c = i * 256 + t;
      int row = c >> 3, col = (c & 7) * 8;
      gload16(Ab + (long)row * lda + k0 + col, &As[c * 8]);
      gload16(Bb + (long)row * ldb + k0 + col, &Bs[c * 8]);
    }
    if constexpr (FILLMODE == 3) {
      const f32x4 fv = {FILLV, FILLV, FILLV, FILLV};
      const long nB = (long)gridDim.x * gridDim.y * gridDim.z;
      long s0 = fillBase + (((long)(k0 >> 6) * nB + p) * 3) * 256 + t;
      __builtin_nontemporal_store(fv, (f32x4*)attn + s0);
      __builtin_nontemporal_store(fv, (f32x4*)attn + s0 + 256);
      __builtin_nontemporal_store(fv, (f32x4*)attn + s0 + 512);
    }
    __syncthreads();
#pragma unroll
    for (int kk = 0; kk < 2; ++kk) {
      bf16x8 af[4], bfr[4];
#pragma unroll
      for (int mi = 0; mi < 4; ++mi)
        af[mi] = *(const bf16x8*)&As[(wm + mi * 16 + (lane & 15)) * 64
                                     + kk * 32 + (lane >> 4) * 8];
#pragma unroll
      for (int ni = 0; ni < 4; ++ni)
        bfr[ni] = *(const bf16x8*)&Bs[(wn + ni * 16 + (lane & 15)) * 64
                                      + kk * 32 + (lane >> 4) * 8];
#pragma unroll
      for (int mi = 0; mi < 4; ++mi)
#pragma unroll
        for (int ni = 0; ni < 4; ++ni)
          acc[mi][ni] = __builtin_amdgcn_mfma_f32_16x16x32_bf16(
              af[mi], bfr[ni], acc[mi][ni], 0, 0, 0);
    }
    __syncthreads();
  }

  if constexpr (FILLMODE == 3) {
    const f32x4 fv = {FILLV, FILLV, FILLV, FILLV};
    f32x4* dst = (f32x4*)attn + fillBase2 + (long)p * fillSlots + t;
    for (int i = 0; i < fillSlots; i += 256)
      __builtin_nontemporal_store(fv, dst + i);
  }

  const long cb = (long)zb * cBatchB + (long)zh * cBatchH;
  const int row0 = blockIdx.y * 128 + wm;
  const int col0 = blockIdx.x * 128 + wn;
#pragma unroll
  for (int mi = 0; mi < 4; ++mi) {
#pragma unroll
    for (int ni = 0; ni < 4; ++ni) {
      const int col = col0 + ni * 16 + (lane & 15);
      const float bv = BIAS ? bias[col] : 0.f;
#pragma unroll
      for (int j = 0; j < 4; ++j) {
        const int row = row0 + mi * 16 + (lane >> 4) * 4 + j;
        float v = acc[mi][ni][j] + bv;
        if (RELU) v = fmaxf(v, 0.f);
        if (OUTF32) ((float*)C)[cb + (long)row * ldc + col] = v;
        else        ((bf16_t*)C)[cb + (long)row * ldc + col] = (bf16_t)v;
      }
    }
  }
}

// ---------------------------------------------------------------------------
// Fused per-head feature map: Out = relu(A @ Wf1 + b1) @ Wf2 + b2. (R5 form)
// ---------------------------------------------------------------------------
__global__ __launch_bounds__(256) void fm_fused(
    const bf16_t* __restrict__ A, const bf16_t* __restrict__ W1t,
    const bf16_t* __restrict__ W2t, const float* __restrict__ b1,
    const float* __restrict__ b2, bf16_t* __restrict__ Out)
{
  __shared__ char Hs[64 * 256 * 2];   // 32 KB
  const int t = threadIdx.x, lane = t & 63, w = t >> 6;
  const long r0 = (long)blockIdx.x * 64;
  const int lr = lane & 15, lk = lane >> 4;

  f32x4 acc[4][4];
#pragma unroll
  for (int i = 0; i < 4; ++i)
#pragma unroll
    for (int j = 0; j < 4; ++j) acc[i][j] = (f32x4){0.f, 0.f, 0.f, 0.f};
  const int wn = w * 64;
#pragma unroll
  for (int kk = 0; kk < 4; ++kk) {
    bf16x8 af[4], bfr[4];
#pragma unroll
    for (int mi = 0; mi < 4; ++mi)
      af[mi] = *(const bf16x8*)&A[(r0 + mi * 16 + lr) * 128 + kk * 32 + lk * 8];
#pragma unroll
    for (int ni = 0; ni < 4; ++ni)
      bfr[ni] = *(const bf16x8*)&W1t[(long)(wn + ni * 16 + lr) * 128
                                     + kk * 32 + lk * 8];
#pragma unroll
    for (int mi = 0; mi < 4; ++mi)
#pragma unroll
      for (int ni = 0; ni < 4; ++ni)
        acc[mi][ni] = __builtin_amdgcn_mfma_f32_16x16x32_bf16(
            af[mi], bfr[ni], acc[mi][ni], 0, 0, 0);
  }
#pragma unroll
  for (int ni = 0; ni < 4; ++ni) {
    const int col = wn + ni * 16 + lr;
    const float bvv = b1[col];
#pragma unroll
    for (int mi = 0; mi < 4; ++mi)
#pragma unroll
      for (int j = 0; j < 4; ++j) {
        const int row = mi * 16 + lk * 4 + j;
        float h = fmaxf(acc[mi][ni][j] + bvv, 0.f);
        int byte = (row << 9) + (col << 1);
        byte ^= (row & 7) << 4;
        *(bf16_t*)(Hs + byte) = (bf16_t)h;
      }
  }
  __syncthreads();

  f32x4 acc2[4][2];
#pragma unroll
  for (int i = 0; i < 4; ++i)
#pragma unroll
    for (int j = 0; j < 2; ++j) acc2[i][j] = (f32x4){0.f, 0.f, 0.f, 0.f};
  const int wn2 = w * 32;
#pragma unroll
  for (int kk = 0; kk < 8; ++kk) {
    bf16x8 af[4], bfr[2];
#pragma unroll
    for (int mi = 0; mi < 4; ++mi) {
      const int m = mi * 16 + lr;
      int byte = (m << 9) + kk * 64 + lk * 16;
      byte ^= (m & 7) << 4;
      af[mi] = *(const bf16x8*)(Hs + byte);
    }
#pragma unroll
    for (int ni = 0; ni < 2; ++ni)
      bfr[ni] = *(const bf16x8*)&W2t[(long)(wn2 + ni * 16 + lr) * 256
                                     + kk * 32 + lk * 8];
#pragma unroll
    for (int mi = 0; mi < 4; ++mi)
#pragma unroll
      for (int ni = 0; ni < 2; ++ni)
        acc2[mi][ni] = __builtin_amdgcn_mfma_f32_16x16x32_bf16(
            af[mi], bfr[ni], acc2[mi][ni], 0, 0, 0);
  }
#pragma unroll
  for (int ni = 0; ni < 2; ++ni) {
    const int col = wn2 + ni * 16 + lr;
    const float bvv = b2[col];
#pragma unroll
    for (int mi = 0; mi < 4; ++mi)
#pragma unroll
      for (int j = 0; j < 4; ++j) {
        const int row = mi * 16 + lk * 4 + j;
        Out[(r0 + row) * 128 + col] = (bf16_t)(acc2[mi][ni][j] + bvv);
      }
  }
}

// ---------------------------------------------------------------------------
// prep: fused fp32->bf16 cvt of q,k,v + all weight transpose-cvts.
// ---------------------------------------------------------------------------
__global__ __launch_bounds__(256) void prep(
    const float* __restrict__ q, const float* __restrict__ k,
    const float* __restrict__ v,
    const float* __restrict__ Wq, const float* __restrict__ Wk,
    const float* __restrict__ Wv, const float* __restrict__ Wo,
    const float* __restrict__ Wf1, const float* __restrict__ Wf2,
    bf16_t* __restrict__ qkv_bf, bf16_t* __restrict__ Wqkv_t,
    bf16_t* __restrict__ Wf1_t, bf16_t* __restrict__ Wf2_t)
{
  const int t = threadIdx.x;
  const int bid = blockIdx.x;
  __shared__ float tile[32][33];

  if (bid < 24576) {
    const float* in = bid < 8192 ? q : (bid < 16384 ? k : v);
    bf16_t* o = qkv_bf + (long)(bid >> 13) * 8388608L;
    long i = ((long)(bid & 8191) * 256 + t) * 4;
    float4 x = *(const float4*)&in[i];
    bf16x4 r = {(bf16_t)x.x, (bf16_t)x.y, (bf16_t)x.z, (bf16_t)x.w};
    *(bf16x4*)&o[i] = r;
    return;
  }

  const int x = t & 31, y = t >> 5;
  const float* W; bf16_t* out; int Kd, Nd, n0, k0;
  if (bid < 40960) {
    const int sub = bid - 24576;
    const int z = sub >> 12, r = sub & 4095;
    W = z == 0 ? Wq : z == 1 ? Wk : z == 2 ? Wv : Wo;
    out = Wqkv_t + (long)z * 4194304L;
    Kd = 2048; Nd = 2048;
    n0 = (r & 63) * 32; k0 = (r >> 6) * 32;
  } else if (bid < 40992) {
    const int sub = bid - 40960;
    W = Wf1; out = Wf1_t; Kd = 128; Nd = 256;
    n0 = (sub & 7) * 32; k0 = (sub >> 3) * 32;
  } else {
    const int sub = bid - 40992;
    W = Wf2; out = Wf2_t; Kd = 256; Nd = 128;
    n0 = (sub & 3) * 32; k0 = (sub >> 2) * 32;
  }
#pragma unroll
  for (int j = 0; j < 32; j += 8)
    tile[y + j][x] = W[(long)(k0 + y + j) * Nd + n0 + x];
  __syncthreads();
#pragma unroll
  for (int j = 0; j < 32; j += 8)
    out[(long)(n0 + y + j) * Kd + k0 + x] = (bf16_t)tile[x][y + j];
}

// ---------------------------------------------------------------------------
// Partial KV^T + per-chunk K-sums. (R5 form)
// ---------------------------------------------------------------------------
__global__ __launch_bounds__(256) void kv_partial(
    const bf16_t* __restrict__ Kf, const bf16_t* __restrict__ Vp,
    float* __restrict__ part, float* __restrict__ part_denom) {
  const int z = blockIdx.y, b = z >> 4, h = z & 15;
  const int s0 = blockIdx.x * 128;
  const int t = threadIdx.x;
  __shared__ bf16_t Ks[32 * 128];
  __shared__ bf16_t Vs[32 * 128];
  __shared__ float red[4];
  const bf16_t* Kb = Kf + (long)b * 4194304 + h * 128;
  const bf16_t* Vb = Vp + (long)b * 4194304 + h * 128;
  float acc[8][8];
#pragma unroll
  for (int i = 0; i < 8; ++i)
#pragma unroll
    for (int j = 0; j < 8; ++j) acc[i][j] = 0.f;
  float ksum = 0.f;
  const int d0 = (t & 15) * 8, e0 = (t >> 4) * 8;
  for (int sc = 0; sc < 128; sc += 32) {
#pragma unroll
    for (int i = 0; i < 2; ++i) {
      int idx = (i * 256 + t) * 8;
      int r = idx >> 7, c = idx & 127;
      long g = (long)(s0 + sc + r) * 2048 + c;
      *(bf16x8*)&Ks[r * 128 + c] = *(const bf16x8*)&Kb[g];
      *(bf16x8*)&Vs[r * 128 + c] = *(const bf16x8*)&Vb[g];
    }
    __syncthreads();
    {
      bf16x8 a0 = *(const bf16x8*)&Ks[t * 16];
      bf16x8 a1 = *(const bf16x8*)&Ks[t * 16 + 8];
#pragma unroll
      for (int j = 0; j < 8; ++j) ksum += (float)a0[j] + (float)a1[j];
    }
    for (int s = 0; s < 32; ++s) {
      bf16x8 kv = *(const bf16x8*)&Ks[s * 128 + d0];
      bf16x8 vv = *(const bf16x8*)&Vs[s * 128 + e0];
      float kf[8], vf[8];
#pragma unroll
      for (int i = 0; i < 8; ++i) { kf[i] = (float)kv[i]; vf[i] = (float)vv[i]; }
#pragma unroll
      for (int i = 0; i < 8; ++i)
#pragma unroll
        for (int j = 0; j < 8; ++j) acc[i][j] += vf[i] * kf[j];
    }
    __syncthreads();
  }

#pragma unroll
  for (int off = 32; off; off >>= 1) ksum += __shfl_down(ksum, off, 64);
  if ((t & 63) == 0) red[t >> 6] = ksum;
  __syncthreads();
  if (t == 0)
    part_denom[blockIdx.x * 32 + z] = red[0] + red[1] + red[2] + red[3];

  float* pb = part + ((long)blockIdx.x * 32 + z) * 16384;
#pragma unroll
  for (int i = 0; i < 8; ++i)
#pragma unroll
    for (int j = 0; j < 8; ++j)
      pb[(e0 + i) * 128 + (d0 + j)] = acc[i][j];
}

// ---------------------------------------------------------------------------
// kv_reduce: 512 blocks; z = bid>>4, slice = bid&15. (R5 form)
// ---------------------------------------------------------------------------
__global__ __launch_bounds__(256) void kv_reduce(
    const float* __restrict__ part, const float* __restrict__ part_denom,
    bf16_t* __restrict__ KVT) {
  const int z = blockIdx.x >> 4, slice = blockIdx.x & 15;
  const int t = threadIdx.x;
  float dsum = 0.f;
#pragma unroll
  for (int c = 0; c < 16; ++c) dsum += part_denom[c * 32 + z];
  const float inv = 1.0f / (dsum + 1e-8f);
  const int base = slice * 1024;
  for (int i = base + t; i < base + 1024; i += 256) {
    float s = 0.f;
#pragma unroll
    for (int c = 0; c < 16; ++c) s += part[((long)c * 32 + z) * 16384 + i];
    KVT[(long)z * 16384 + i] = (bf16_t)(s * inv);
  }
}

// ---------------------------------------------------------------------------
extern "C" void kernel_launch(void* const* d_in, const int* in_sizes, int n_in,
                              void* d_out, int out_size, void* d_ws, size_t ws_size,
                              hipStream_t stream) {
  (void)in_sizes; (void)n_in; (void)out_size; (void)ws_size;
  const float* q   = (const float*)d_in[0];
  const float* k   = (const float*)d_in[1];
  const float* v   = (const float*)d_in[2];
  const float* Wq  = (const float*)d_in[3];
  const float* bq  = (const float*)d_in[4];
  const float* Wk  = (const float*)d_in[5];
  const float* bk  = (const float*)d_in[6];
  const float* Wv  = (const float*)d_in[7];
  const float* bv  = (const float*)d_in[8];
  const float* Wo  = (const float*)d_in[9];
  const float* bo  = (const float*)d_in[10];
  const float* Wf1 = (const float*)d_in[11];
  const float* bf1 = (const float*)d_in[12];
  const float* Wf2 = (const float*)d_in[13];
  const float* bf2 = (const float*)d_in[14];

  bf16_t* P      = (bf16_t*)d_ws;
  bf16_t* qkv_bf = P;                  // [3][4096][2048]
  bf16_t* Wqkv_t = P + 25165824L;      // [4][2048][2048]
  bf16_t* Wo_t   = P + 37748736L;
  bf16_t* Wf1_t  = P + 41943040L;      // [256][128]
  bf16_t* Wf2_t  = P + 41975808L;      // [128][256]
  bf16_t* Qp     = P + 42008576L;      // [12288][2048] stacked Qp,Kp,Vp
  bf16_t* Vp     = P + 58785792L;      // later reused as context
  bf16_t* Qf     = P + 83951616L;      // [131072][128] stacked Qf,Kf
  bf16_t* Kf     = P + 92340224L;
  bf16_t* KVT    = P + 100728832L;     // [32][128][128]
  float*  part   = (float*)d_ws;       // [16][32][128][128] f32
  float*  part_denom = (float*)d_ws + 8388608L;   // [16][32]

  float* out0 = (float*)d_out;                 // [2,2048,2048]
  float* attn = (float*)d_out + 8388608L;      // [2,16,2048,2048]

  dim3 blk(256);

  // 1. prep: cvt q/k/v + weight transposes
  prep<<<41024, blk, 0, stream>>>(q, k, v, Wq, Wk, Wv, Wo, Wf1, Wf2,
                                  qkv_bf, Wqkv_t, Wf1_t, Wf2_t);

  // 2. 8-phase fused Q/K/V projection (+ fill [0, 18874368) in-loop)
  proj_gemm8<<<384, 512, 0, stream>>>(qkv_bf, Wqkv_t, bq, bk, bv, Qp, attn);

  // 3. fused feature map over Qp||Kp -> Qf||Kf
  fm_fused<<<2048, blk, 0, stream>>>(Qp, Wf1_t, Wf2_t, bf1, bf2, Qf);

  // 4. KV^T partials + K-sums
  kv_partial<<<dim3(16, 32), blk, 0, stream>>>(Kf, Vp, part, part_denom);

  // 5. reduce partials (+denom)
  kv_reduce<<<512, blk, 0, stream>>>(part, part_denom, KVT);

  // 6. context = Qf @ KVT^T batched over 32 (b,h)
  gemm_bt<false, false, false, 0><<<dim3(1, 16, 32), blk, 0, stream>>>(
      Qf, KVT, nullptr, Vp, 128, 2048, 128, 2048,
      4194304L, 128L, 262144L, 16384L, 4194304L, 128L, 16,
      nullptr, 0, 0, 0);

  // 7. output = context @ Wo + bo
  //    (+ fill [18874368, 31457280) in-loop + [31457280, 33554432) epilogue)
  gemm_bt<false, true, true, 3><<<dim3(16, 32, 1), blk, 0, stream>>>(
      Vp, Wo_t, bo, out0, 2048, 2048, 2048, 2048, 0, 0, 0, 0, 0, 0, 1,
      attn, 18874368L, 31457280L, 4096);
}